// Round 11
// baseline (193.053 us; speedup 1.0000x reference)
//
#include <hip/hip_runtime.h>

typedef unsigned short u16;
typedef unsigned int   u32;

using bf16x8 = __attribute__((ext_vector_type(8))) __bf16;
using f32x4  = __attribute__((ext_vector_type(4))) float;
using f32x16 = __attribute__((ext_vector_type(16))) float;
using u32x4  = __attribute__((ext_vector_type(4))) u32;

#define DEV static __device__ __forceinline__
#define GP(p) (const __attribute__((address_space(1))) void*)(p)
#define LP(p) (__attribute__((address_space(3))) void*)(p)
// fused counted-wait + barrier (T4)
#define WAITB(N) asm volatile("s_waitcnt vmcnt(" N ")\n\ts_barrier" ::: "memory")
// counted VMEM wait for reg-staged loads; sched_barrier pins register-only consumers (rule #18)
#define WAITVM(N) do{ asm volatile("s_waitcnt vmcnt(" N ")" ::: "memory"); \
                      __builtin_amdgcn_sched_barrier(0); }while(0)
// end-of-step: drain LDS ops then barrier
#define LGKMB asm volatile("s_waitcnt lgkmcnt(0)\n\ts_barrier" ::: "memory")

DEV u16 f2bf(float f){                      // RNE float->bf16
  u32 u = __builtin_bit_cast(u32, f);
  u32 r = u + 0x7fffu + ((u>>16)&1u);
  return (u16)(r>>16);
}
DEV float bcf(u32 x){ return __builtin_bit_cast(float, x); }
DEV bf16x8 as_bf(uint4 v){ return __builtin_bit_cast(bf16x8, v); }
DEV u32 cvt_pk(float lo, float hi){
  u32 r;
  asm("v_cvt_pk_bf16_f32 %0, %1, %2" : "=v"(r) : "v"(lo), "v"(hi));
  return r;
}
DEV void plswap(u32 &a, u32 &b){
  auto r = __builtin_amdgcn_permlane32_swap((int)a, (int)b, false, false);
  a = (u32)r[0]; b = (u32)r[1];
}
DEV float fexp2(float x){ float r; asm("v_exp_f32 %0, %1" : "=v"(r) : "v"(x)); return r; }
DEV float max3f(float a, float b, float c){
  float r; asm("v_max3_f32 %0, %1, %2, %3" : "=v"(r) : "v"(a), "v"(b), "v"(c)); return r;
}
DEV float fractf_(float x){ float r; asm("v_fract_f32 %0, %1" : "=v"(r) : "v"(x)); return r; }
DEV float sinrev(float f){ float r; asm("v_sin_f32 %0, %1" : "=v"(r) : "v"(f)); return r; }
DEV float cosrev(float f){ float r; asm("v_cos_f32 %0, %1" : "=v"(r) : "v"(f)); return r; }

// problem constants
constexpr int CB = 4, CL = 2048, CE = 1024, CH = 16, CD = 64;
constexpr int CM = CB*CL;           // 8192 rows
constexpr float LOG2E  = 1.44269504088896f;
constexpr float NEGBIG = -1.44269504e9f;    // -1e9 * log2e (exp2 domain)
constexpr float INV2PI = 0.15915494309189535f;

// ---------------- prep: cast q/k/v + wq/wk/wv to bf16, and mask detect+convert ----------------
// blocks [0,27648): cast (3*2^21 qkv + 3*2^18 weight float4 items)
// blocks [27648,27680): mask detect + convert (32 blocks x 256 = 8192 entries)
__global__ void prep_kernel(const float* __restrict__ q, const float* __restrict__ k,
                            const float* __restrict__ v,
                            const float* __restrict__ wq, const float* __restrict__ wk,
                            const float* __restrict__ wv,
                            u16* __restrict__ oq, u16* __restrict__ ok, u16* __restrict__ ov,
                            u16* __restrict__ owq, u16* __restrict__ owk, u16* __restrict__ owv,
                            const void* __restrict__ mask, float* __restrict__ maskf){
  if (blockIdx.x < 27648){
    int i = blockIdx.x*blockDim.x + threadIdx.x;
    const float* in; u16* out; int j;
    if (i < 3*(1<<21)){
      int w = i >> 21; j = i & ((1<<21)-1);
      in = (w==0)?q:(w==1)?k:v; out = (w==0)?oq:(w==1)?ok:ov;
    } else {
      int r = i - 3*(1<<21);
      int w = r >> 18; j = r & ((1<<18)-1);
      in = (w==0)?wq:(w==1)?wk:wv; out = (w==0)?owq:(w==1)?owk:owv;
    }
    float4 a = ((const float4*)in)[j];
    ushort4 h;
    h.x = f2bf(a.x); h.y = f2bf(a.y); h.z = f2bf(a.z); h.w = f2bf(a.w);
    ((ushort4*)out)[j] = h;
    return;
  }
  __shared__ int a_gt1, a_badf, a_oddnz, a_evennz;
  if (threadIdx.x==0){ a_gt1=0; a_badf=0; a_oddnz=0; a_evennz=0; }
  __syncthreads();
  const u32* w = (const u32*)mask;
  int gt1=0, badf=0, oddnz=0, evennz=0;
  for (int i=threadIdx.x; i<2048; i+=256){
    u32 x = w[i];
    if (x > 1u) gt1 = 1;
    if (x != 0u && x != 0x3f800000u) badf = 1;
    if (x != 0u){ if (i & 1) oddnz = 1; else evennz = 1; }
  }
  if (gt1) atomicOr(&a_gt1,1);
  if (badf) atomicOr(&a_badf,1);
  if (oddnz) atomicOr(&a_oddnz,1);
  if (evennz) atomicOr(&a_evennz,1);
  __syncthreads();
  int mode;
  if (!a_gt1)           mode = (!a_oddnz && a_evennz) ? 3 : 0;
  else if (!a_badf)     mode = 1;
  else                  mode = 2;
  int i = (blockIdx.x-27648)*blockDim.x + threadIdx.x;   // B*L
  int val;
  if      (mode==0) val = ((const int*)mask)[i] != 0;
  else if (mode==1) val = ((const float*)mask)[i] != 0.f;
  else if (mode==3) val = ((const int*)mask)[2*i] != 0;
  else              val = ((const unsigned char*)mask)[i] != 0;
  maskf[i] = val ? NEGBIG : 0.f;
}

#define CVTW(dst, lo4, hi4) do{ \
  dst.x = cvt_pk(bcf(lo4.x), bcf(lo4.y)); \
  dst.y = cvt_pk(bcf(lo4.z), bcf(lo4.w)); \
  dst.z = cvt_pk(bcf(hi4.x), bcf(hi4.y)); \
  dst.w = cvt_pk(bcf(hi4.z), bcf(hi4.w)); \
}while(0)

// ---------------- QKV projection GEMM, all-bf16 inputs (R3 proven, 75us) ----------------
// 256x128 tile, 8 waves, BK=64, RING-3 counted-vmcnt pipeline:
// stage tile t+2 at top of step t (6 gload_lds/thread), WAITB(6) at step end
// confirms tile t+1 (issued ~2 steps earlier, covers HBM latency);
// 6 loads stay in flight across every barrier (never drain to 0 mid-loop).
// Banking: 128B LDS rows, 16B-chunk ^= row&7 both sides (measured 0 conflicts).
// Grid: 256 blocks/z (768 total) at 1 block/CU (144KB LDS) = exactly 3.0 rounds.
// z=0: Q = qbf@wq^T+bq, scaled 0.125*log2e, RoPE, pack [B,H,L,D]
// z=1: K = kbf@wk^T+bk, RoPE, pack [B,H,L,D]
// z=2: Vt = (wvb@vbf^T)+bv[row], bf16 [E][CM] (pre-transposed V)
__global__ __launch_bounds__(512) void gemm_qkv(
    const u16* __restrict__ qbf, const u16* __restrict__ kbf, const u16* __restrict__ vbf,
    const u16* __restrict__ wqb, const u16* __restrict__ wkb, const u16* __restrict__ wvb,
    const float* __restrict__ bq, const float* __restrict__ bk, const float* __restrict__ bv,
    u16* __restrict__ Qp, u16* __restrict__ Kp, u16* __restrict__ Vt, int zbase)
{
  __shared__ u16 As[3][16384];   // ring of [256 rows][64 k] swizzled tiles (32KB)
  __shared__ u16 Bs[3][8192];    // ring of [128 rows][64 k] swizzled tiles (16KB)
  const int z = zbase + blockIdx.y;
  const int tid=threadIdx.x, lane=tid&63, wid=tid>>6;
  const int llo=lane&15, lhi=lane>>4;
  const u16* A; const u16* Bt;
  if (z==0){ A=qbf; Bt=wqb; }
  else if (z==1){ A=kbf; Bt=wkb; }
  else { A=wvb; Bt=vbf; }
  // XCD supertile swizzle: each XCD owns a contiguous block region (L2 reuse)
  int bid = blockIdx.x;                  // [0,256) per z
  int xcd = bid&7, j = bid>>3;           // j in [0,32)
  int mb, nb;
  if (z<2){ mb = xcd*4 + (j>>3); nb = j&7; }     // 32 x 8 tiles of 256x128
  else    { mb = j&3;  nb = xcd*8 + (j>>2); }    // 4 x 64 tiles (M=1024, N=8192)
  const int m0 = mb*256, n0 = nb*128;
  const int wr = wid>>1, wc = wid&1;     // 4M x 2N wave grid, 64x64 per wave
  const int rswA = llo&7;                // read-side XOR (rows within 8-stripe)

  auto STAGE = [&](int t, int buf){      // 6 gload_lds / thread (A:4, B:2)
    #pragma unroll
    for (int i=0;i<4;i++){
      int c = tid + i*512;               // A: 2048 chunks of 16B
      int row = c>>3, ch = c&7;
      int sc = ch ^ (row&7);             // inverse-swizzled source chunk
      __builtin_amdgcn_global_load_lds(GP(A + (size_t)(m0+row)*CE + t*64 + sc*8),
                                       LP(&As[buf][c*8]), 16, 0, 0);
    }
    #pragma unroll
    for (int i=0;i<2;i++){
      int c = tid + i*512;               // B: 1024 chunks of 16B
      int row = c>>3, ch = c&7;
      int sc = ch ^ (row&7);
      __builtin_amdgcn_global_load_lds(GP(Bt + (size_t)(n0+row)*CE + t*64 + sc*8),
                                       LP(&Bs[buf][c*8]), 16, 0, 0);
    }
  };

  f32x4 acc[4][4] = {};

  auto COMP = [&](int buf){
    const char* as = (const char*)As[buf];
    const char* bs = (const char*)Bs[buf];
    #pragma unroll
    for (int ks=0; ks<2; ks++){
      bf16x8 af[4], bf_[4];
      #pragma unroll
      for (int mr=0;mr<4;mr++){
        int r = wr*64+mr*16+llo;
        af[mr] = as_bf(*(const uint4*)(as + r*128 + (((ks*4+lhi)^rswA)<<4)));
      }
      #pragma unroll
      for (int nr=0;nr<4;nr++){
        int r = wc*64+nr*16+llo;
        bf_[nr] = as_bf(*(const uint4*)(bs + r*128 + (((ks*4+lhi)^rswA)<<4)));
      }
      #pragma unroll
      for (int mr=0;mr<4;mr++)
        #pragma unroll
        for (int nr=0;nr<4;nr++)
          acc[mr][nr] = __builtin_amdgcn_mfma_f32_16x16x32_bf16(af[mr], bf_[nr], acc[mr][nr], 0,0,0);
    }
  };

  // prologue: tiles 0,1 in flight (12 loads); wait 6 -> tile 0 landed
  STAGE(0,0); STAGE(1,1);
  WAITB("6");

  // Ring reuse: STAGE(t+2) rewrites buf[(t+2)%3] = buf[(t-1)%3], whose last reads
  // (COMP(t-1)) completed before the end-of-(t-1) barrier preceding this issue.
  #pragma unroll 1
  for (int t=0; t<14; t++){
    STAGE(t+2, (t+2)%3);
    COMP(t%3);
    WAITB("6");                          // tile t+1 landed; t+2 (6 loads) in flight
  }
  COMP(2); WAITB("0");                   // t=14 (buf 2); drain tile 15
  COMP(0);                               // t=15 (buf 0); epilogue touches no LDS

  const int colbase = n0 + wc*64;
  if (z < 2){
    const float* bias = z ? bk : bq;
    u16* outp = z ? Kp : Qp;
    const float scale = z ? 1.f : 0.125f*LOG2E;
    const int h = colbase >> 6;           // wave covers exactly one head
    float b1[2], b2[2], invr[2];
    #pragma unroll
    for (int nr=0;nr<2;nr++){
      int j2 = nr*16 + llo;
      b1[nr] = bias[colbase + j2];
      b2[nr] = bias[colbase + j2 + 32];
      // 10000^{-j2/32} / (2*pi): angle in revolutions per unit l
      invr[nr] = exp2f(-(float)j2 * 0.41524101186092033f) * INV2PI;
    }
    #pragma unroll
    for (int mr=0;mr<4;mr++)
      #pragma unroll
      for (int r=0;r<4;r++){
        int row = m0 + wr*64 + mr*16 + lhi*4 + r;
        int b = row >> 11, l = row & 2047;
        u16* dst = outp + (((size_t)(b*CH + h)*CL + l) << 6);
        #pragma unroll
        for (int nr=0;nr<2;nr++){
          int j2 = nr*16 + llo;
          float x1 = (acc[mr][nr][r]   + b1[nr]) * scale;
          float x2 = (acc[mr][nr+2][r] + b2[nr]) * scale;
          float fr = fractf_((float)l * invr[nr]);
          float sn = sinrev(fr), cs = cosrev(fr);
          dst[j2]      = f2bf(x1*cs - x2*sn);
          dst[j2 + 32] = f2bf(x2*cs + x1*sn);
        }
      }
  } else {
    #pragma unroll
    for (int mr=0;mr<4;mr++)
      #pragma unroll
      for (int r=0;r<4;r++){
        int row = m0 + wr*64 + mr*16 + lhi*4 + r;
        float bvv = bv[row];
        #pragma unroll
        for (int nr=0;nr<4;nr++){
          int col = colbase + nr*16 + llo;
          Vt[(size_t)row*CM + col] = f2bf(acc[mr][nr][r] + bvv);
        }
      }
  }
}

// ---------------- output projection GEMM (fp32 out, bias per col) ----------------
// A = AO bf16 via global_load_lds ring-3; B = wo fp32 reg-staged (cast in staging).
__global__ __launch_bounds__(512) void gemm_out(
    const u16* __restrict__ A, const float* __restrict__ Btf,
    const float* __restrict__ bias, float* __restrict__ C)
{
  __shared__ u16 As[3][16384];   // 48KB
  __shared__ u16 Bs[2][8192];    // 32KB
  const int tid=threadIdx.x, lane=tid&63, wid=tid>>6;
  const int llo=lane&15, lhi=lane>>4;
  int bid = blockIdx.x;
  int xcd = bid&7, j = bid>>3;
  const int m0 = (xcd*4 + (j>>3))*256, n0 = (j&7)*128;   // 32 x 8 tiles of 256x128
  const int wr = wid>>1, wc = wid&1;
  const int rswA = llo&7;

  auto STAGEA = [&](int t, int buf){     // 4 gload_lds / thread
    #pragma unroll
    for (int i=0;i<4;i++){
      int c = tid + i*512, row=c>>3, sc=(c&7)^(row&7);
      __builtin_amdgcn_global_load_lds(GP(A + (size_t)(m0+row)*CE + t*64 + sc*8),
                                       LP(&As[buf][c*8]), 16, 0, 0);
    }
  };

  const float* bptr[2]; int bco[2];
  #pragma unroll
  for (int i=0;i<2;i++){
    int c = tid + i*512, row=c>>3, sc=(c&7)^(row&7);
    bptr[i] = Btf + (size_t)(n0+row)*CE + sc*8;
    bco[i] = c*8;
  }
  u32x4 B0[4], B1[4];

#define LOADB(T, RB) do{ \
  _Pragma("unroll") \
  for (int i=0;i<2;i++){ \
    asm volatile("global_load_dwordx4 %0, %2, off\n\tglobal_load_dwordx4 %1, %2, off offset:16" \
      : "=&v"((RB)[2*i]), "=&v"((RB)[2*i+1]) : "v"(bptr[i] + (size_t)(T)*64) : "memory"); \
  } \
}while(0)

#define WRITEB(BUF, RB) do{ \
  _Pragma("unroll") \
  for (int i=0;i<2;i++){ \
    u32x4 w; CVTW(w, (RB)[2*i], (RB)[2*i+1]); \
    *(u32x4*)&Bs[BUF][bco[i]] = w; \
  } \
}while(0)

  f32x4 acc[4][4] = {};

  auto COMP = [&](int abuf, int bbuf){
    const char* as = (const char*)As[abuf];
    const char* bs = (const char*)Bs[bbuf];
    #pragma unroll
    for (int ks=0; ks<2; ks++){
      bf16x8 af[4], bf_[4];
      #pragma unroll
      for (int mr=0;mr<4;mr++){
        int r = wr*64+mr*16+llo;
        af[mr] = as_bf(*(const uint4*)(as + r*128 + (((ks*4+lhi)^rswA)<<4)));
      }
      #pragma unroll
      for (int nr=0;nr<4;nr++){
        int r = wc*64+nr*16+llo;
        bf_[nr] = as_bf(*(const uint4*)(bs + r*128 + (((ks*4+lhi)^rswA)<<4)));
      }
      #pragma unroll
      for (int mr=0;mr<4;mr++)
        #pragma unroll
        for (int nr=0;nr<4;nr++)
          acc[mr][nr] = __builtin_amdgcn_mfma_f32_16x16x32_bf16(af[mr], bf_[nr], acc[mr][nr], 0,0,0);
    }
  };

  // prologue: A(0),B(0),A(1),B(1) in flight; confirm tile0 pair, write B0
  STAGEA(0,0); LOADB(0, B0);
  STAGEA(1,1); LOADB(1, B1);
  WAITVM("8");
  WRITEB(0, B0);
  LGKMB;

  #pragma unroll 1
  for (int jj=0; jj<7; jj++){
    const int t = 2*jj;
    STAGEA(t+2, (t+2)%3); LOADB(t+2, B0);
    WAITVM("8");
    WRITEB(1, B1);
    COMP(t%3, 0);
    LGKMB;
    STAGEA(t+3, (t+3)%3); LOADB(t+3, B1);
    WAITVM("8");
    WRITEB(0, B0);
    COMP((t+1)%3, 1);
    LGKMB;
  }
  WAITVM("0");
  WRITEB(1, B1);
  COMP(2, 0);          // t=14
  LGKMB;
  COMP(0, 1);          // t=15

#undef LOADB
#undef WRITEB

  #pragma unroll
  for (int mr=0;mr<4;mr++)
    #pragma unroll
    for (int nr=0;nr<4;nr++)
      #pragma unroll
      for (int r=0;r<4;r++){
        int row = m0 + wr*64 + mr*16 + lhi*4 + r;
        int col = n0 + wc*64 + nr*16 + llo;
        C[(size_t)row*CE + col] = acc[mr][nr][r] + bias[col];
      }
}

// ---------------- flash attention, T15 software pipeline ----------------
// Qp,Kp: [B*H, L, D] bf16 (Q pre-scaled by 0.125*log2e). Vt: [E, CM] bf16. Out AO [B,L,E] bf16.
__global__ __launch_bounds__(256,2) void attn_kernel(
    const u16* __restrict__ Qp, const u16* __restrict__ Kp, const u16* __restrict__ Vt,
    const float* __restrict__ maskf, u16* __restrict__ AO)
{
  __shared__ u16 K_lds[4][4096];   // ring of [kv64][d64] swizzled tiles
  __shared__ u16 V_lds[4][4096];   // ring of [d64][kv64] swizzled tiles
  __shared__ float M_lds[2048];    // padding mask row (exp2 domain) for this batch
  const int bh = blockIdx.x;
  const int slot = blockIdx.y;
  const int b = bh >> 4, h = bh & 15;
  const int tid=threadIdx.x, lane=tid&63, wid=tid>>6;
  const int l31 = lane&31, hi = lane>>5;
  const u16* Qh = Qp + (size_t)bh*CL*CD;
  const u16* Kh = Kp + (size_t)bh*CL*CD;
  const u16* Vhd = Vt + (size_t)(h*CD)*CM + b*CL;

  // stage padding-mask row once (8KB); confirmed by the first WAITB.
  #pragma unroll
  for (int i=0;i<2;i++)
    __builtin_amdgcn_global_load_lds(GP(maskf + b*CL + (i*256+tid)*4),
                                     LP(&M_lds[(i*256+tid)*4]), 16, 0, 0);

  auto STAGE = [&](int t, int buf){   // 4 gload_lds instructions per wave
    const u16* Ksrc = Kh + t*64*CD;
    const u16* Vsrc = Vhd + t*64;
    #pragma unroll
    for (int i=0;i<2;i++){
      int c = tid + i*256;
      int row = c>>3, sc = c&7;
      int c16 = sc ^ (row&7);
      __builtin_amdgcn_global_load_lds(GP(Ksrc + row*CD + c16*8),
                                       LP(&K_lds[buf][c*8]), 16, 0, 0);
      __builtin_amdgcn_global_load_lds(GP(Vsrc + (size_t)row*CM + c16*8),
                                       LP(&V_lds[buf][c*8]), 16, 0, 0);
    }
  };

  const int rowb = l31*128;            // LDS row byte base
  const int rsw  = (l31&7)<<4;
  const int qts2[2] = {15-slot, slot};

  for (int qi=0; qi<2; qi++){
    const int qt = qts2[qi];
    const int qw0 = qt*128 + wid*32;
    const int qlane = qw0 + l31;

    bf16x8 qf[4];
    #pragma unroll
    for (int c=0;c<4;c++)
      qf[c] = as_bf(*(const uint4*)(Qh + (size_t)qlane*CD + c*16 + hi*8));

    f32x16 o0 = {}, o1 = {};
    float m_r = -3e38f, l_r = 0.f;
    f32x16 sA0, sA1, sB0, sB1;         // double-banked S tiles

    const int nt = qt*2 + 2;
    STAGE(0,0); STAGE(1,1);

    // QK^T for tile t -> (d0,d1); Q carries 0.125*log2e
    auto QK = [&](int t, f32x16& d0, f32x16& d1){
      const char* kb = (const char*)K_lds[t&3];
      f32x16 z0 = {}, z1 = {};
      __builtin_amdgcn_s_setprio(1);
      #pragma unroll
      for (int c=0;c<4;c++){
        int cb = (c*32 + hi*16) ^ rsw;
        bf16x8 k0 = as_bf(*(const uint4*)(kb + rowb + cb));
        bf16x8 k1 = as_bf(*(const uint4*)(kb + 4096 + rowb + cb));
        z0 = __builtin_amdgcn_mfma_f32_32x32x16_bf16(k0, qf[c], z0, 0,0,0);
        z1 = __builtin_amdgcn_mfma_f32_32x32x16_bf16(k1, qf[c], z1, 0,0,0);
      }
      __builtin_amdgcn_s_setprio(0);
      d0 = z0; d1 = z1;
    };

    // softmax + PV for tile tp (S banks passed by ref; runs while QK(tp+1) drains)
    auto SMPV = [&](int tp, f32x16& s0, f32x16& s1){
      const int kv0 = tp*64;
      const char* vb = (const char*)V_lds[tp&3];

      // padding mask (broadcast LDS reads)
      f32x4 cm[8];
      #pragma unroll
      for (int s2=0;s2<2;s2++)
        #pragma unroll
        for (int g=0; g<4; g++)
          cm[s2*4+g] = *(const f32x4*)&M_lds[kv0 + s2*32 + g*8 + hi*4];

      // mask (+ causal on diagonal tiles), in place (exp2 domain)
      if (kv0 + 63 > qw0){
        #pragma unroll
        for (int s2=0;s2<2;s2++){
          f32x16& sv = s2 ? s1 : s0;
          #pragma unroll
          for (int reg=0; reg<16; reg++){
            int k = kv0 + s2*32 + (reg&3) + (reg>>2)*8 + hi*4;
            float v = sv[reg] + cm[s2*4+(reg>>2)][reg&3];
            sv[reg] = (k > qlane) ? v + NEGBIG : v;
          }
        }
      } else {
        #pragma unroll
        for (int s2=0;s2<2;s2++){
          f32x16& sv = s2 ? s1 : s0;
          #pragma unroll
          for (int reg=0; reg<16; reg++)
            sv[reg] = sv[reg] + cm[s2*4+(reg>>2)][reg&3];
        }
      }

      // row max
      f32x16 mx;
      #pragma unroll
      for (int r=0;r<16;r++) mx[r] = fmaxf(s0[r], s1[r]);
      float a0 = max3f(mx[0],mx[1],mx[2]);
      float a1 = max3f(mx[3],mx[4],mx[5]);
      float a2 = max3f(mx[6],mx[7],mx[8]);
      float a3 = max3f(mx[9],mx[10],mx[11]);
      float a4 = max3f(mx[12],mx[13],mx[14]);
      float vmax = fmaxf(max3f(a0,a1,a2), max3f(a3,a4,mx[15]));
      vmax = fmaxf(vmax, __shfl_xor(vmax, 32));

      // defer-max (T13)
      if (__any(vmax > m_r + 12.0f)){
        float mnew = fmaxf(m_r, vmax);
        float sc = fexp2(m_r - mnew);
        l_r *= sc;
        o0 *= sc; o1 *= sc;
        m_r = mnew;
      }

      // p = exp2(v - m)
      #pragma unroll
      for (int r=0;r<16;r++){
        s0[r] = fexp2(s0[r] - m_r);
        s1[r] = fexp2(s1[r] - m_r);
      }
      // row sum
      f32x16 sm = s0 + s1;
      #pragma unroll
      for (int w=8; w>=1; w>>=1)
        #pragma unroll
        for (int r=0;r<w;r++) sm[r] = sm[r] + sm[r+w];
      float rsum = sm[0];
      rsum += __shfl_xor(rsum, 32);
      l_r += rsum;

      // P -> bf16 B-fragments in-register
      u32 w_[16];
      #pragma unroll
      for (int s2=0;s2<2;s2++){
        f32x16& sv = s2 ? s1 : s0;
        #pragma unroll
        for (int c=0;c<2;c++){
          u32 a  = cvt_pk(sv[c*8+0], sv[c*8+1]);
          u32 bb = cvt_pk(sv[c*8+2], sv[c*8+3]);
          u32 cc = cvt_pk(sv[c*8+4], sv[c*8+5]);
          u32 dd = cvt_pk(sv[c*8+6], sv[c*8+7]);
          plswap(a, cc); plswap(bb, dd);
          int base = (s2*2+c)*4;
          w_[base+0]=a; w_[base+1]=bb; w_[base+2]=cc; w_[base+3]=dd;
        }
      }

      // O^T += V^T @ P^T
      __builtin_amdgcn_s_setprio(1);
      #pragma unroll
      for (int kc=0; kc<4; kc++){
        bf16x8 pf = as_bf(make_uint4(w_[kc*4], w_[kc*4+1], w_[kc*4+2], w_[kc*4+3]));
        int cb = (kc*32 + hi*16) ^ rsw;
        bf16x8 v0 = as_bf(*(const uint4*)(vb + rowb + cb));
        bf16x8 v1 = as_bf(*(const uint4*)(vb + 4096 + rowb + cb));
        o0 = __builtin_amdgcn_mfma_f32_32x32x16_bf16(v0, pf, o0, 0,0,0);
        o1 = __builtin_amdgcn_mfma_f32_32x32x16_bf16(v1, pf, o1, 0,0,0);
      }
      __builtin_amdgcn_s_setprio(0);
    };

    // t=0: QK only
    WAITB("4");                          // confirms S(0) (+mask, +qf)
    if (2 < nt) STAGE(2,2);
    QK(0, sA0, sA1);

    // pairs t=(2j+1, 2j+2), static S-bank parity
    #pragma unroll 1
    for (int jx=0; jx<qt; jx++){
      int t = 2*jx+1;                    // odd -> bank B
      WAITB("4");
      if (t+2 < nt) STAGE(t+2,(t+2)&3);
      QK(t, sB0, sB1);
      SMPV(t-1, sA0, sA1);
      t = 2*jx+2;                        // even -> bank A (never the last tile)
      WAITB("4");
      if (t+2 < nt) STAGE(t+2,(t+2)&3);
      QK(t, sA0, sA1);
      SMPV(t-1, sB0, sB1);
    }
    // t = nt-1 (odd)
    WAITB("0");
    QK(nt-1, sB0, sB1);
    SMPV(nt-2, sA0, sA1);
    // finish last tile
    SMPV(nt-1, sB0, sB1);

    // normalize + write O^T: lane has q=qlane, d = mt*32 + g*8 + hi*4 + {0..3}
    float inv = 1.f / l_r;
    u16* dst = AO + (size_t)(b*CL + qlane)*CE + h*CD;
    #pragma unroll
    for (int mt=0; mt<2; mt++){
      f32x16& ov = mt ? o1 : o0;
      #pragma unroll
      for (int g=0; g<4; g++){
        u32 lo  = cvt_pk(ov[g*4+0]*inv, ov[g*4+1]*inv);
        u32 hi2 = cvt_pk(ov[g*4+2]*inv, ov[g*4+3]*inv);
        *(uint2*)(dst + mt*32 + g*8 + hi*4) = make_uint2(lo, hi2);
      }
    }
    // protect ring reuse by qi=1 prologue (and reset vmcnt ledger)
    __syncthreads();
  }
}

// ---------------- launcher ----------------
extern "C" void kernel_launch(void* const* d_in, const int* in_sizes, int n_in,
                              void* d_out, int out_size, void* d_ws, size_t ws_size,
                              hipStream_t stream) {
  const float* query = (const float*)d_in[0];
  const float* key_  = (const float*)d_in[1];
  const float* value = (const float*)d_in[2];
  const float* wq = (const float*)d_in[3];
  const float* bq = (const float*)d_in[4];
  const float* wk = (const float*)d_in[5];
  const float* bk = (const float*)d_in[6];
  const float* wv = (const float*)d_in[7];
  const float* bv = (const float*)d_in[8];
  const float* wo = (const float*)d_in[9];
  const float* bo = (const float*)d_in[10];
  const void*  kpm = d_in[11];

  char* ws = (char*)d_ws;
  constexpr size_t SZ_ME_BF = (size_t)CM*CE*2;    // 16 MiB
  constexpr size_t SZ_EE_BF = (size_t)CE*CE*2;    // 2 MiB
  constexpr size_t OFF_MASKF= 256;
  constexpr size_t OFF_B0   = 65536;              // qbf; later AO
  constexpr size_t OFF_B1   = OFF_B0 + SZ_ME_BF;  // kbf
  constexpr size_t OFF_B2   = OFF_B1 + SZ_ME_BF;  // vbf; later Qp (fallback path)
  constexpr size_t OFF_WQ   = OFF_B2 + SZ_ME_BF;
  constexpr size_t OFF_WK   = OFF_WQ + SZ_EE_BF;
  constexpr size_t OFF_WV   = OFF_WK + SZ_EE_BF;
  constexpr size_t OFF_KP   = OFF_WV + SZ_EE_BF;  // Kp
  constexpr size_t OFF_VT   = OFF_KP + SZ_ME_BF;  // Vt [1024][8192]
  constexpr size_t OFF_QP   = OFF_VT + SZ_ME_BF;  // dedicated Qp (if ws allows)

  float* maskf = (float*)(ws + OFF_MASKF);
  u16*  qbf = (u16*)(ws + OFF_B0);
  u16*  kbf = (u16*)(ws + OFF_B1);
  u16*  vbf = (u16*)(ws + OFF_B2);
  u16*  wqb = (u16*)(ws + OFF_WQ);
  u16*  wkb = (u16*)(ws + OFF_WK);
  u16*  wvb = (u16*)(ws + OFF_WV);
  u16*  Kp  = (u16*)(ws + OFF_KP);
  u16*  Vt  = (u16*)(ws + OFF_VT);
  u16*  AO  = qbf;                   // alias: qbf dead after gemm_qkv completes

  prep_kernel<<<27680,256,0,stream>>>(query, key_, value, wq, wk, wv,
                                      qbf, kbf, vbf, wqb, wkb, wvb, kpm, maskf);

  u16* Qp;
  if (ws_size >= OFF_QP + SZ_ME_BF){
    // dedicated Qp buffer: all three projections in one launch (no alias hazard)
    Qp = (u16*)(ws + OFF_QP);
    gemm_qkv<<<dim3(256,3),512,0,stream>>>(qbf, kbf, vbf, wqb, wkb, wvb,
                                           bq, bk, bv, Qp, Kp, Vt, 0);
  } else {
    // fallback: Qp aliases vbf -> V (and K) must complete before Q projection
    Qp = vbf;
    gemm_qkv<<<dim3(256,2),512,0,stream>>>(qbf, kbf, vbf, wqb, wkb, wvb,
                                           bq, bk, bv, Qp, Kp, Vt, 1);
    gemm_qkv<<<dim3(256,1),512,0,stream>>>(qbf, kbf, vbf, wqb, wkb, wvb,
                                           bq, bk, bv, Qp, Kp, Vt, 0);
  }

  attn_kernel<<<dim3(CB*CH, 8),256,0,stream>>>(Qp, Kp, Vt, maskf, AO);

  gemm_out<<<256,512,0,stream>>>(AO, wo, bo, (float*)d_out);
}

// Round 12
// 180.632 us; speedup vs baseline: 1.0688x; 1.0688x over previous
//
#include <hip/hip_runtime.h>

typedef unsigned short u16;
typedef unsigned int   u32;

using bf16x8 = __attribute__((ext_vector_type(8))) __bf16;
using f32x4  = __attribute__((ext_vector_type(4))) float;
using f32x16 = __attribute__((ext_vector_type(16))) float;
using u32x4  = __attribute__((ext_vector_type(4))) u32;

#define DEV static __device__ __forceinline__
#define GP(p) (const __attribute__((address_space(1))) void*)(p)
#define LP(p) (__attribute__((address_space(3))) void*)(p)
// fused counted-wait + barrier (T4)
#define WAITB(N) asm volatile("s_waitcnt vmcnt(" N ")\n\ts_barrier" ::: "memory")
// counted VMEM wait for reg-staged loads; sched_barrier pins register-only consumers (rule #18)
#define WAITVM(N) do{ asm volatile("s_waitcnt vmcnt(" N ")" ::: "memory"); \
                      __builtin_amdgcn_sched_barrier(0); }while(0)
// end-of-step: drain LDS ops then barrier
#define LGKMB asm volatile("s_waitcnt lgkmcnt(0)\n\ts_barrier" ::: "memory")

DEV u16 f2bf(float f){                      // RNE float->bf16
  u32 u = __builtin_bit_cast(u32, f);
  u32 r = u + 0x7fffu + ((u>>16)&1u);
  return (u16)(r>>16);
}
DEV float bcf(u32 x){ return __builtin_bit_cast(float, x); }
DEV bf16x8 as_bf(uint4 v){ return __builtin_bit_cast(bf16x8, v); }
DEV u32 cvt_pk(float lo, float hi){
  u32 r;
  asm("v_cvt_pk_bf16_f32 %0, %1, %2" : "=v"(r) : "v"(lo), "v"(hi));
  return r;
}
DEV void plswap(u32 &a, u32 &b){
  auto r = __builtin_amdgcn_permlane32_swap((int)a, (int)b, false, false);
  a = (u32)r[0]; b = (u32)r[1];
}
DEV float fexp2(float x){ float r; asm("v_exp_f32 %0, %1" : "=v"(r) : "v"(x)); return r; }
DEV float max3f(float a, float b, float c){
  float r; asm("v_max3_f32 %0, %1, %2, %3" : "=v"(r) : "v"(a), "v"(b), "v"(c)); return r;
}
DEV float fractf_(float x){ float r; asm("v_fract_f32 %0, %1" : "=v"(r) : "v"(x)); return r; }
DEV float sinrev(float f){ float r; asm("v_sin_f32 %0, %1" : "=v"(r) : "v"(f)); return r; }
DEV float cosrev(float f){ float r; asm("v_cos_f32 %0, %1" : "=v"(r) : "v"(f)); return r; }

// problem constants
constexpr int CB = 4, CL = 2048, CE = 1024, CH = 16, CD = 64;
constexpr int CM = CB*CL;           // 8192 rows
constexpr float LOG2E  = 1.44269504088896f;
constexpr float NEGBIG = -1.44269504e9f;    // -1e9 * log2e (exp2 domain)
constexpr float INV2PI = 0.15915494309189535f;

// ---------------- mask detect+convert AND weight cast, one launch ----------------
// blocks [0,3072): cast wq/wk/wv fp32->bf16 (3*2^18 float4 items)
// blocks [3072,3104): mask detect + convert (32 blocks x 256 = 8192 entries)
__global__ void prep_kernel(const float* __restrict__ wq, const float* __restrict__ wk,
                            const float* __restrict__ wv,
                            u16* __restrict__ oq, u16* __restrict__ ok, u16* __restrict__ ov,
                            const void* __restrict__ mask, float* __restrict__ maskf){
  if (blockIdx.x < 3072){
    int i = blockIdx.x*blockDim.x + threadIdx.x;
    int w = i >> 18, j = i & ((1<<18)-1);
    const float* in = (w==0)?wq:(w==1)?wk:wv;
    u16* out = (w==0)?oq:(w==1)?ok:ov;
    float4 a = ((const float4*)in)[j];
    ushort4 h;
    h.x = f2bf(a.x); h.y = f2bf(a.y); h.z = f2bf(a.z); h.w = f2bf(a.w);
    ((ushort4*)out)[j] = h;
    return;
  }
  __shared__ int a_gt1, a_badf, a_oddnz, a_evennz;
  if (threadIdx.x==0){ a_gt1=0; a_badf=0; a_oddnz=0; a_evennz=0; }
  __syncthreads();
  const u32* w = (const u32*)mask;
  int gt1=0, badf=0, oddnz=0, evennz=0;
  for (int i=threadIdx.x; i<2048; i+=256){
    u32 v = w[i];
    if (v > 1u) gt1 = 1;
    if (v != 0u && v != 0x3f800000u) badf = 1;
    if (v != 0u){ if (i & 1) oddnz = 1; else evennz = 1; }
  }
  if (gt1) atomicOr(&a_gt1,1);
  if (badf) atomicOr(&a_badf,1);
  if (oddnz) atomicOr(&a_oddnz,1);
  if (evennz) atomicOr(&a_evennz,1);
  __syncthreads();
  int mode;
  if (!a_gt1)           mode = (!a_oddnz && a_evennz) ? 3 : 0;
  else if (!a_badf)     mode = 1;
  else                  mode = 2;
  int i = (blockIdx.x-3072)*blockDim.x + threadIdx.x;   // B*L
  int v;
  if      (mode==0) v = ((const int*)mask)[i] != 0;
  else if (mode==1) v = ((const float*)mask)[i] != 0.f;
  else if (mode==3) v = ((const int*)mask)[2*i] != 0;
  else              v = ((const unsigned char*)mask)[i] != 0;
  maskf[i] = v ? NEGBIG : 0.f;
}

#define CVTW(dst, lo4, hi4) do{ \
  dst.x = cvt_pk(bcf(lo4.x), bcf(lo4.y)); \
  dst.y = cvt_pk(bcf(lo4.z), bcf(lo4.w)); \
  dst.z = cvt_pk(bcf(hi4.x), bcf(hi4.y)); \
  dst.w = cvt_pk(bcf(hi4.z), bcf(hi4.w)); \
}while(0)

// ---------------- QKV projection GEMM, hybrid staging + TRIPLE reg sets ----------------
// 256x128 tile, 8 waves, BK=64. Reused operand = bf16 via global_load_lds; streamed
// operand = fp32 reg-staged with cast-in-staging. 3 rotating reg sets so the
// fp32 stream's load is issued TWO steps before its confirming wait (2 steps ~
// 800-1000cyc >= HBM latency), with issues ordered (lds-op, reg-op) so the FIFO
// wait never force-confirms a young reg set. vmcnt ledgers hand-traced per step.
//  z<2 : A = activation fp32 reg-staged (8 ld/thr, sets S0/S1/S2),
//        B = weight bf16 gload_lds ring-4 (2 ld/thr).
//  z==2: A = wvb bf16 gload_lds ring-3 (4 ld/thr),
//        B = value fp32 reg-staged (4 ld/thr, sets R0/R1/R2).
// LDS 128KB carved per z. Banking: 128B rows, chunk ^= row&7 both sides (0 conflicts).
__global__ __launch_bounds__(512) void gemm_qkv(
    const float* __restrict__ query, const float* __restrict__ keyp,
    const float* __restrict__ value,
    const u16* __restrict__ wqb, const u16* __restrict__ wkb, const u16* __restrict__ wvb,
    const float* __restrict__ bq, const float* __restrict__ bk, const float* __restrict__ bv,
    u16* __restrict__ Qp, u16* __restrict__ Kp, u16* __restrict__ Vt)
{
  __shared__ u16 LDSU[65536];    // 128KB, carved per z
  const int z = blockIdx.y;
  const int tid=threadIdx.x, lane=tid&63, wid=tid>>6;
  const int llo=lane&15, lhi=lane>>4;
  int bid = blockIdx.x;                  // [0,256) per z
  int xcd = bid&7, j = bid>>3;           // j in [0,32)
  int mb, nb;
  if (z<2){ mb = xcd*4 + (j>>3); nb = j&7; }     // 32 x 8 tiles of 256x128
  else    { mb = j&3;  nb = xcd*8 + (j>>2); }    // 4 x 64 tiles (M=1024, N=8192)
  const int m0 = mb*256, n0 = nb*128;
  const int wr = wid>>1, wc = wid&1;     // 4M x 2N wave grid, 64x64 per wave
  const int rswA = llo&7;

  f32x4 acc[4][4] = {};

  auto COMP = [&](const u16* asrc, const u16* bsrc){
    const char* as = (const char*)asrc;
    const char* bs = (const char*)bsrc;
    #pragma unroll
    for (int ks=0; ks<2; ks++){
      bf16x8 af[4], bf_[4];
      #pragma unroll
      for (int mr=0;mr<4;mr++){
        int r = wr*64+mr*16+llo;
        af[mr] = as_bf(*(const uint4*)(as + r*128 + (((ks*4+lhi)^rswA)<<4)));
      }
      #pragma unroll
      for (int nr=0;nr<4;nr++){
        int r = wc*64+nr*16+llo;
        bf_[nr] = as_bf(*(const uint4*)(bs + r*128 + (((ks*4+lhi)^rswA)<<4)));
      }
      #pragma unroll
      for (int mr=0;mr<4;mr++)
        #pragma unroll
        for (int nr=0;nr<4;nr++)
          acc[mr][nr] = __builtin_amdgcn_mfma_f32_16x16x32_bf16(af[mr], bf_[nr], acc[mr][nr], 0,0,0);
    }
  };

  if (z < 2){
    const float* Af = z ? keyp : query;
    const u16*  Wb  = z ? wkb : wqb;
    u16* As0 = &LDSU[0];
    u16* As1 = &LDSU[16384];
    // B ring-4 slot s: &LDSU[32768 + s*8192]

    const float* aptr[4]; int aco[4];
    #pragma unroll
    for (int i=0;i<4;i++){
      int c = tid + i*512, row=c>>3, sc=(c&7)^(row&7);
      aptr[i] = Af + (size_t)(m0+row)*CE + sc*8;
      aco[i] = c*8;
    }
    u32x4 S0[8], S1[8], S2[8];           // TRIPLE reg sets: A(t) lives 3 steps

#define LOADA(T, RA) do{ \
  _Pragma("unroll") \
  for (int i=0;i<4;i++){ \
    asm volatile("global_load_dwordx4 %0, %2, off\n\tglobal_load_dwordx4 %1, %2, off offset:16" \
      : "=&v"((RA)[2*i]), "=&v"((RA)[2*i+1]) : "v"(aptr[i] + (size_t)(T)*64) : "memory"); \
  } \
}while(0)

#define STAGEB(T, SLOT) do{ \
  _Pragma("unroll") \
  for (int i=0;i<2;i++){ \
    int c = tid + i*512, row=c>>3, sc=(c&7)^(row&7); \
    __builtin_amdgcn_global_load_lds(GP(Wb + (size_t)(n0+row)*CE + (T)*64 + sc*8), \
                                     LP(&LDSU[32768 + (SLOT)*8192 + c*8]), 16, 0, 0); \
  } \
}while(0)

#define WRITEA(DST, RA) do{ \
  u16* _d = (DST); \
  _Pragma("unroll") \
  for (int i=0;i<4;i++){ \
    u32x4 w; CVTW(w, (RA)[2*i], (RA)[2*i+1]); \
    *(u32x4*)&_d[aco[i]] = w; \
  } \
}while(0)

// step T (0..12): stage B(T+2), issue A(T+3) into SL, wait WN (confirms through
// A(T+1), covering B(T)), flush A(T+1) from SW to LDS, compute tile T, barrier.
#define QSTEP(T, SL, SW, WN) do{ \
  STAGEB((T)+2, ((T)+2)&3); \
  LOADA((T)+3, SL); \
  WAITVM(WN); \
  WRITEA(((((T)+1)&1)?As1:As0), SW); \
  COMP((((T)&1)?As1:As0), &LDSU[32768 + ((T)&3)*8192]); \
  LGKMB; \
}while(0)

    // prologue: A0,B0,B1,A1,A2 in flight (28 loads); confirm A0 only (leave 20)
    LOADA(0, S0); STAGEB(0, 0); STAGEB(1, 1);
    LOADA(1, S1); LOADA(2, S2);
    WAITVM("20");
    WRITEA(As0, S0);
    LGKMB;

    QSTEP(0,  S0, S1, "18");   // A3->S0, flush A1
    QSTEP(1,  S1, S2, "20");   // A4->S1, flush A2
    QSTEP(2,  S2, S0, "20");
    QSTEP(3,  S0, S1, "20");
    QSTEP(4,  S1, S2, "20");
    QSTEP(5,  S2, S0, "20");
    QSTEP(6,  S0, S1, "20");
    QSTEP(7,  S1, S2, "20");
    QSTEP(8,  S2, S0, "20");
    QSTEP(9,  S0, S1, "20");
    QSTEP(10, S1, S2, "20");
    QSTEP(11, S2, S0, "20");
    QSTEP(12, S0, S1, "20");   // A15->S0, flush A13
    // t=13: stage B15 only; confirm through A14 (covers B13); flush A14
    STAGEB(15, 3);
    WAITVM("12");
    WRITEA(As0, S2);           // A14 -> As[14&1]=As0
    COMP(As1, &LDSU[32768 + 1*8192]);   // tile 13, slot 1
    LGKMB;
    // t=14: confirm through A15 (covers B14); flush A15
    WAITVM("2");
    WRITEA(As1, S0);           // A15 -> As[15&1]=As1
    COMP(As0, &LDSU[32768 + 2*8192]);   // tile 14, slot 2
    LGKMB;
    // t=15
    WAITVM("0");
    COMP(As1, &LDSU[32768 + 3*8192]);   // tile 15, slot 3

#undef LOADA
#undef STAGEB
#undef WRITEA
#undef QSTEP

    // ---- epilogue: bias + scale + RoPE + pack [B,H,L,D]
    const int colbase = n0 + wc*64;
    const float* bias = z ? bk : bq;
    u16* outp = z ? Kp : Qp;
    const float scale = z ? 1.f : 0.125f*LOG2E;
    const int h = colbase >> 6;           // wave covers exactly one head
    float b1[2], b2[2], invr[2];
    #pragma unroll
    for (int nr=0;nr<2;nr++){
      int j2 = nr*16 + llo;
      b1[nr] = bias[colbase + j2];
      b2[nr] = bias[colbase + j2 + 32];
      invr[nr] = exp2f(-(float)j2 * 0.41524101186092033f) * INV2PI;  // 10000^{-j2/32}/(2pi)
    }
    #pragma unroll
    for (int mr=0;mr<4;mr++)
      #pragma unroll
      for (int r=0;r<4;r++){
        int row = m0 + wr*64 + mr*16 + lhi*4 + r;
        int b = row >> 11, l = row & 2047;
        u16* dst = outp + (((size_t)(b*CH + h)*CL + l) << 6);
        #pragma unroll
        for (int nr=0;nr<2;nr++){
          int j2 = nr*16 + llo;
          float x1 = (acc[mr][nr][r]   + b1[nr]) * scale;
          float x2 = (acc[mr][nr+2][r] + b2[nr]) * scale;
          float fr = fractf_((float)l * invr[nr]);
          float sn = sinrev(fr), cs = cosrev(fr);
          dst[j2]      = f2bf(x1*cs - x2*sn);
          dst[j2 + 32] = f2bf(x2*cs + x1*sn);
        }
      }
  } else {
    // z==2: A = wvb bf16 gload_lds ring-3 (slots 0..2 at s*16384),
    //       B = value fp32 reg-staged, TRIPLE sets R0/R1/R2, dbuf Bs0/Bs1.
    u16* Bs0 = &LDSU[49152];
    u16* Bs1 = &LDSU[57344];

    const float* bptr[2]; int bco[2];
    #pragma unroll
    for (int i=0;i<2;i++){
      int c = tid + i*512, row=c>>3, sc=(c&7)^(row&7);
      bptr[i] = value + (size_t)(n0+row)*CE + sc*8;
      bco[i] = c*8;
    }
    u32x4 R0[4], R1[4], R2[4];

#define STAGEA(T, SLOT) do{ \
  _Pragma("unroll") \
  for (int i=0;i<4;i++){ \
    int c = tid + i*512, row=c>>3, sc=(c&7)^(row&7); \
    __builtin_amdgcn_global_load_lds(GP(wvb + (size_t)(m0+row)*CE + (T)*64 + sc*8), \
                                     LP(&LDSU[(SLOT)*16384 + c*8]), 16, 0, 0); \
  } \
}while(0)

#define LOADB(T, RB) do{ \
  _Pragma("unroll") \
  for (int i=0;i<2;i++){ \
    asm volatile("global_load_dwordx4 %0, %2, off\n\tglobal_load_dwordx4 %1, %2, off offset:16" \
      : "=&v"((RB)[2*i]), "=&v"((RB)[2*i+1]) : "v"(bptr[i] + (size_t)(T)*64) : "memory"); \
  } \
}while(0)

#define WRITEB(DST, RB) do{ \
  u16* _d = (DST); \
  _Pragma("unroll") \
  for (int i=0;i<2;i++){ \
    u32x4 w; CVTW(w, (RB)[2*i], (RB)[2*i+1]); \
    *(u32x4*)&_d[bco[i]] = w; \
  } \
}while(0)

// step T (0..12): stage A(T+2), issue B(T+3) into SL, wait WN (confirms through
// B(T+1), covering A(T)), flush B(T+1) from SW, compute tile T, barrier.
#define VSTEP(T, SL, SW, WN) do{ \
  STAGEA((T)+2, ((T)+2)%3); \
  LOADB((T)+3, SL); \
  WAITVM(WN); \
  WRITEB(((((T)+1)&1)?Bs1:Bs0), SW); \
  COMP(&LDSU[(((T))%3)*16384], (((T)&1)?Bs1:Bs0)); \
  LGKMB; \
}while(0)

    // prologue: A0,B0,A1,B1,B2 in flight (20 loads); confirm through B0 (leave 12)
    STAGEA(0,0); LOADB(0, R0);
    STAGEA(1,1); LOADB(1, R1);
    LOADB(2, R2);
    WAITVM("12");
    WRITEB(Bs0, R0);
    LGKMB;

    VSTEP(0,  R0, R1, "12");   // B3->R0, flush B1
    VSTEP(1,  R1, R2, "16");   // B4->R1, flush B2
    VSTEP(2,  R2, R0, "16");
    VSTEP(3,  R0, R1, "16");
    VSTEP(4,  R1, R2, "16");
    VSTEP(5,  R2, R0, "16");
    VSTEP(6,  R0, R1, "16");
    VSTEP(7,  R1, R2, "16");
    VSTEP(8,  R2, R0, "16");
    VSTEP(9,  R0, R1, "16");
    VSTEP(10, R1, R2, "16");
    VSTEP(11, R2, R0, "16");
    VSTEP(12, R0, R1, "16");   // B15->R0, flush B13
    // t=13: stage A15 only; confirm through B14 (covers A13); flush B14
    STAGEA(15, 0);
    WAITVM("12");
    WRITEB(Bs0, R2);           // B14 -> Bs[14&1]=Bs0
    COMP(&LDSU[1*16384], Bs1); // tile 13: A slot 13%3=1, Bs[13&1]=Bs1
    LGKMB;
    // t=14: confirm through B15 (covers A14); flush B15
    WAITVM("4");
    WRITEB(Bs1, R0);           // B15 -> Bs[15&1]=Bs1
    COMP(&LDSU[2*16384], Bs0); // tile 14: A slot 2, Bs0
    LGKMB;
    // t=15
    WAITVM("0");
    COMP(&LDSU[0*16384], Bs1); // tile 15: A slot 0, Bs1

#undef STAGEA
#undef LOADB
#undef WRITEB
#undef VSTEP

    // ---- epilogue: bias per row, write Vt [E][CM]
    const int colbase = n0 + wc*64;
    #pragma unroll
    for (int mr=0;mr<4;mr++)
      #pragma unroll
      for (int r=0;r<4;r++){
        int row = m0 + wr*64 + mr*16 + lhi*4 + r;
        float bvv = bv[row];
        #pragma unroll
        for (int nr=0;nr<4;nr++){
          int col = colbase + nr*16 + llo;
          Vt[(size_t)row*CM + col] = f2bf(acc[mr][nr][r] + bvv);
        }
      }
  }
}

// ---------------- output projection GEMM (fp32 out, bias per col) ----------------
// A = AO bf16 via global_load_lds ring-3; B = wo fp32 reg-staged (cast in staging).
__global__ __launch_bounds__(512) void gemm_out(
    const u16* __restrict__ A, const float* __restrict__ Btf,
    const float* __restrict__ bias, float* __restrict__ C)
{
  __shared__ u16 As[3][16384];   // 48KB
  __shared__ u16 Bs[2][8192];    // 32KB
  const int tid=threadIdx.x, lane=tid&63, wid=tid>>6;
  const int llo=lane&15, lhi=lane>>4;
  int bid = blockIdx.x;
  int xcd = bid&7, j = bid>>3;
  const int m0 = (xcd*4 + (j>>3))*256, n0 = (j&7)*128;   // 32 x 8 tiles of 256x128
  const int wr = wid>>1, wc = wid&1;
  const int rswA = llo&7;

  auto STAGEA = [&](int t, int buf){     // 4 gload_lds / thread
    #pragma unroll
    for (int i=0;i<4;i++){
      int c = tid + i*512, row=c>>3, sc=(c&7)^(row&7);
      __builtin_amdgcn_global_load_lds(GP(A + (size_t)(m0+row)*CE + t*64 + sc*8),
                                       LP(&As[buf][c*8]), 16, 0, 0);
    }
  };

  const float* bptr[2]; int bco[2];
  #pragma unroll
  for (int i=0;i<2;i++){
    int c = tid + i*512, row=c>>3, sc=(c&7)^(row&7);
    bptr[i] = Btf + (size_t)(n0+row)*CE + sc*8;
    bco[i] = c*8;
  }
  u32x4 B0[4], B1[4];

#define LOADB(T, RB) do{ \
  _Pragma("unroll") \
  for (int i=0;i<2;i++){ \
    asm volatile("global_load_dwordx4 %0, %2, off\n\tglobal_load_dwordx4 %1, %2, off offset:16" \
      : "=&v"((RB)[2*i]), "=&v"((RB)[2*i+1]) : "v"(bptr[i] + (size_t)(T)*64) : "memory"); \
  } \
}while(0)

#define WRITEB(BUF, RB) do{ \
  _Pragma("unroll") \
  for (int i=0;i<2;i++){ \
    u32x4 w; CVTW(w, (RB)[2*i], (RB)[2*i+1]); \
    *(u32x4*)&Bs[BUF][bco[i]] = w; \
  } \
}while(0)

  f32x4 acc[4][4] = {};

  auto COMP = [&](int abuf, int bbuf){
    const char* as = (const char*)As[abuf];
    const char* bs = (const char*)Bs[bbuf];
    #pragma unroll
    for (int ks=0; ks<2; ks++){
      bf16x8 af[4], bf_[4];
      #pragma unroll
      for (int mr=0;mr<4;mr++){
        int r = wr*64+mr*16+llo;
        af[mr] = as_bf(*(const uint4*)(as + r*128 + (((ks*4+lhi)^rswA)<<4)));
      }
      #pragma unroll
      for (int nr=0;nr<4;nr++){
        int r = wc*64+nr*16+llo;
        bf_[nr] = as_bf(*(const uint4*)(bs + r*128 + (((ks*4+lhi)^rswA)<<4)));
      }
      #pragma unroll
      for (int mr=0;mr<4;mr++)
        #pragma unroll
        for (int nr=0;nr<4;nr++)
          acc[mr][nr] = __builtin_amdgcn_mfma_f32_16x16x32_bf16(af[mr], bf_[nr], acc[mr][nr], 0,0,0);
    }
  };

  // prologue: A(0),B(0),A(1),B(1) in flight; confirm tile0 pair, write B0
  STAGEA(0,0); LOADB(0, B0);
  STAGEA(1,1); LOADB(1, B1);
  WAITVM("8");
  WRITEB(0, B0);
  LGKMB;

  #pragma unroll 1
  for (int jj=0; jj<7; jj++){
    const int t = 2*jj;
    STAGEA(t+2, (t+2)%3); LOADB(t+2, B0);
    WAITVM("8");
    WRITEB(1, B1);
    COMP(t%3, 0);
    LGKMB;
    STAGEA(t+3, (t+3)%3); LOADB(t+3, B1);
    WAITVM("8");
    WRITEB(0, B0);
    COMP((t+1)%3, 1);
    LGKMB;
  }
  WAITVM("0");
  WRITEB(1, B1);
  COMP(2, 0);          // t=14
  LGKMB;
  COMP(0, 1);          // t=15

#undef LOADB
#undef WRITEB

  #pragma unroll
  for (int mr=0;mr<4;mr++)
    #pragma unroll
    for (int nr=0;nr<4;nr++)
      #pragma unroll
      for (int r=0;r<4;r++){
        int row = m0 + wr*64 + mr*16 + lhi*4 + r;
        int col = n0 + wc*64 + nr*16 + llo;
        C[(size_t)row*CE + col] = acc[mr][nr][r] + bias[col];
      }
}

// ---------------- flash attention, T15 software pipeline ----------------
// Qp,Kp: [B*H, L, D] bf16 (Q pre-scaled by 0.125*log2e). Vt: [E, CM] bf16. Out AO [B,L,E] bf16.
__global__ __launch_bounds__(256,2) void attn_kernel(
    const u16* __restrict__ Qp, const u16* __restrict__ Kp, const u16* __restrict__ Vt,
    const float* __restrict__ maskf, u16* __restrict__ AO)
{
  __shared__ u16 K_lds[4][4096];   // ring of [kv64][d64] swizzled tiles
  __shared__ u16 V_lds[4][4096];   // ring of [d64][kv64] swizzled tiles
  __shared__ float M_lds[2048];    // padding mask row (exp2 domain) for this batch
  const int bh = blockIdx.x;
  const int slot = blockIdx.y;
  const int b = bh >> 4, h = bh & 15;
  const int tid=threadIdx.x, lane=tid&63, wid=tid>>6;
  const int l31 = lane&31, hi = lane>>5;
  const u16* Qh = Qp + (size_t)bh*CL*CD;
  const u16* Kh = Kp + (size_t)bh*CL*CD;
  const u16* Vhd = Vt + (size_t)(h*CD)*CM + b*CL;

  // stage padding-mask row once (8KB); confirmed by the first WAITB.
  #pragma unroll
  for (int i=0;i<2;i++)
    __builtin_amdgcn_global_load_lds(GP(maskf + b*CL + (i*256+tid)*4),
                                     LP(&M_lds[(i*256+tid)*4]), 16, 0, 0);

  auto STAGE = [&](int t, int buf){   // 4 gload_lds instructions per wave
    const u16* Ksrc = Kh + t*64*CD;
    const u16* Vsrc = Vhd + t*64;
    #pragma unroll
    for (int i=0;i<2;i++){
      int c = tid + i*256;
      int row = c>>3, sc = c&7;
      int c16 = sc ^ (row&7);
      __builtin_amdgcn_global_load_lds(GP(Ksrc + row*CD + c16*8),
                                       LP(&K_lds[buf][c*8]), 16, 0, 0);
      __builtin_amdgcn_global_load_lds(GP(Vsrc + (size_t)row*CM + c16*8),
                                       LP(&V_lds[buf][c*8]), 16, 0, 0);
    }
  };

  const int rowb = l31*128;            // LDS row byte base
  const int rsw  = (l31&7)<<4;
  const int qts2[2] = {15-slot, slot};

  for (int qi=0; qi<2; qi++){
    const int qt = qts2[qi];
    const int qw0 = qt*128 + wid*32;
    const int qlane = qw0 + l31;

    bf16x8 qf[4];
    #pragma unroll
    for (int c=0;c<4;c++)
      qf[c] = as_bf(*(const uint4*)(Qh + (size_t)qlane*CD + c*16 + hi*8));

    f32x16 o0 = {}, o1 = {};
    float m_r = -3e38f, l_r = 0.f;
    f32x16 sA0, sA1, sB0, sB1;         // double-banked S tiles

    const int nt = qt*2 + 2;
    STAGE(0,0); STAGE(1,1);

    // QK^T for tile t -> (d0,d1); Q carries 0.125*log2e
    auto QK = [&](int t, f32x16& d0, f32x16& d1){
      const char* kb = (const char*)K_lds[t&3];
      f32x16 z0 = {}, z1 = {};
      __builtin_amdgcn_s_setprio(1);
      #pragma unroll
      for (int c=0;c<4;c++){
        int cb = (c*32 + hi*16) ^ rsw;
        bf16x8 k0 = as_bf(*(const uint4*)(kb + rowb + cb));
        bf16x8 k1 = as_bf(*(const uint4*)(kb + 4096 + rowb + cb));
        z0 = __builtin_amdgcn_mfma_f32_32x32x16_bf16(k0, qf[c], z0, 0,0,0);
        z1 = __builtin_amdgcn_mfma_f32_32x32x16_bf16(k1, qf[c], z1, 0,0,0);
      }
      __builtin_amdgcn_s_setprio(0);
      d0 = z0; d1 = z1;
    };

    // softmax + PV for tile tp (S banks passed by ref; runs while QK(tp+1) drains)
    auto SMPV = [&](int tp, f32x16& s0, f32x16& s1){
      const int kv0 = tp*64;
      const char* vb = (const char*)V_lds[tp&3];

      // padding mask (broadcast LDS reads)
      f32x4 cm[8];
      #pragma unroll
      for (int s2=0;s2<2;s2++)
        #pragma unroll
        for (int g=0; g<4; g++)
          cm[s2*4+g] = *(const f32x4*)&M_lds[kv0 + s2*32 + g*8 + hi*4];

      // mask (+ causal on diagonal tiles), in place (exp2 domain)
      if (kv0 + 63 > qw0){
        #pragma unroll
        for (int s2=0;s2<2;s2++){
          f32x16& sv = s2 ? s1 : s0;
          #pragma unroll
          for (int reg=0; reg<16; reg++){
            int k = kv0 + s2*32 + (reg&3) + (reg>>2)*8 + hi*4;
            float v = sv[reg] + cm[s2*4+(reg>>2)][reg&3];
            sv[reg] = (k > qlane) ? v + NEGBIG : v;
          }
        }
      } else {
        #pragma unroll
        for (int s2=0;s2<2;s2++){
          f32x16& sv = s2 ? s1 : s0;
          #pragma unroll
          for (int reg=0; reg<16; reg++)
            sv[reg] = sv[reg] + cm[s2*4+(reg>>2)][reg&3];
        }
      }

      // row max
      f32x16 mx;
      #pragma unroll
      for (int r=0;r<16;r++) mx[r] = fmaxf(s0[r], s1[r]);
      float a0 = max3f(mx[0],mx[1],mx[2]);
      float a1 = max3f(mx[3],mx[4],mx[5]);
      float a2 = max3f(mx[6],mx[7],mx[8]);
      float a3 = max3f(mx[9],mx[10],mx[11]);
      float a4 = max3f(mx[12],mx[13],mx[14]);
      float vmax = fmaxf(max3f(a0,a1,a2), max3f(a3,a4,mx[15]));
      vmax = fmaxf(vmax, __shfl_xor(vmax, 32));

      // defer-max (T13)
      if (__any(vmax > m_r + 12.0f)){
        float mnew = fmaxf(m_r, vmax);
        float sc = fexp2(m_r - mnew);
        l_r *= sc;
        o0 *= sc; o1 *= sc;
        m_r = mnew;
      }

      // p = exp2(v - m)
      #pragma unroll
      for (int r=0;r<16;r++){
        s0[r] = fexp2(s0[r] - m_r);
        s1[r] = fexp2(s1[r] - m_r);
      }
      // row sum
      f32x16 sm = s0 + s1;
      #pragma unroll
      for (int w=8; w>=1; w>>=1)
        #pragma unroll
        for (int r=0;r<w;r++) sm[r] = sm[r] + sm[r+w];
      float rsum = sm[0];
      rsum += __shfl_xor(rsum, 32);
      l_r += rsum;

      // P -> bf16 B-fragments in-register
      u32 w_[16];
      #pragma unroll
      for (int s2=0;s2<2;s2++){
        f32x16& sv = s2 ? s1 : s0;
        #pragma unroll
        for (int c=0;c<2;c++){
          u32 a  = cvt_pk(sv[c*8+0], sv[c*8+1]);
          u32 bb = cvt_pk(sv[c*8+2], sv[c*8+3]);
          u32 cc = cvt_pk(sv[c*8+4], sv[c*8+5]);
          u32 dd = cvt_pk(sv[c*8+6], sv[c*8+7]);
          plswap(a, cc); plswap(bb, dd);
          int base = (s2*2+c)*4;
          w_[base+0]=a; w_[base+1]=bb; w_[base+2]=cc; w_[base+3]=dd;
        }
      }

      // O^T += V^T @ P^T
      __builtin_amdgcn_s_setprio(1);
      #pragma unroll
      for (int kc=0; kc<4; kc++){
        bf16x8 pf = as_bf(make_uint4(w_[kc*4], w_[kc*4+1], w_[kc*4+2], w_[kc*4+3]));
        int cb = (kc*32 + hi*16) ^ rsw;
        bf16x8 v0 = as_bf(*(const uint4*)(vb + rowb + cb));
        bf16x8 v1 = as_bf(*(const uint4*)(vb + 4096 + rowb + cb));
        o0 = __builtin_amdgcn_mfma_f32_32x32x16_bf16(v0, pf, o0, 0,0,0);
        o1 = __builtin_amdgcn_mfma_f32_32x32x16_bf16(v1, pf, o1, 0,0,0);
      }
      __builtin_amdgcn_s_setprio(0);
    };

    // t=0: QK only
    WAITB("4");                          // confirms S(0) (+mask, +qf)
    if (2 < nt) STAGE(2,2);
    QK(0, sA0, sA1);

    // pairs t=(2j+1, 2j+2), static S-bank parity
    #pragma unroll 1
    for (int jx=0; jx<qt; jx++){
      int t = 2*jx+1;                    // odd -> bank B
      WAITB("4");
      if (t+2 < nt) STAGE(t+2,(t+2)&3);
      QK(t, sB0, sB1);
      SMPV(t-1, sA0, sA1);
      t = 2*jx+2;                        // even -> bank A (never the last tile)
      WAITB("4");
      if (t+2 < nt) STAGE(t+2,(t+2)&3);
      QK(t, sA0, sA1);
      SMPV(t-1, sB0, sB1);
    }
    // t = nt-1 (odd)
    WAITB("0");
    QK(nt-1, sB0, sB1);
    SMPV(nt-2, sA0, sA1);
    // finish last tile
    SMPV(nt-1, sB0, sB1);

    // normalize + write O^T: lane has q=qlane, d = mt*32 + g*8 + hi*4 + {0..3}
    float inv = 1.f / l_r;
    u16* dst = AO + (size_t)(b*CL + qlane)*CE + h*CD;
    #pragma unroll
    for (int mt=0; mt<2; mt++){
      f32x16& ov = mt ? o1 : o0;
      #pragma unroll
      for (int g=0; g<4; g++){
        u32 lo  = cvt_pk(ov[g*4+0]*inv, ov[g*4+1]*inv);
        u32 hi2 = cvt_pk(ov[g*4+2]*inv, ov[g*4+3]*inv);
        *(uint2*)(dst + mt*32 + g*8 + hi*4) = make_uint2(lo, hi2);
      }
    }
    // protect ring reuse by qi=1 prologue (and reset vmcnt ledger)
    __syncthreads();
  }
}

// ---------------- launcher ----------------
extern "C" void kernel_launch(void* const* d_in, const int* in_sizes, int n_in,
                              void* d_out, int out_size, void* d_ws, size_t ws_size,
                              hipStream_t stream) {
  const float* query = (const float*)d_in[0];
  const float* key_  = (const float*)d_in[1];
  const float* value = (const float*)d_in[2];
  const float* wq = (const float*)d_in[3];
  const float* bq = (const float*)d_in[4];
  const float* wk = (const float*)d_in[5];
  const float* bk = (const float*)d_in[6];
  const float* wv = (const float*)d_in[7];
  const float* bv = (const float*)d_in[8];
  const float* wo = (const float*)d_in[9];
  const float* bo = (const float*)d_in[10];
  const void*  kpm = d_in[11];

  char* ws = (char*)d_ws;
  constexpr size_t SZ_ME_BF = (size_t)CM*CE*2;    // 16 MiB
  constexpr size_t OFF_MASKF= 256;
  constexpr size_t OFF_AO   = 65536;              // attn output, bf16 [B,L,E]
  constexpr size_t OFF_KP   = OFF_AO + SZ_ME_BF;
  constexpr size_t OFF_VT   = OFF_KP + SZ_ME_BF;  // Vt [1024][8192]
  constexpr size_t OFF_QP   = OFF_VT + SZ_ME_BF;

  float* maskf = (float*)(ws + OFF_MASKF);
  u16*  AO  = (u16*)(ws + OFF_AO);
  u16*  Kp  = (u16*)(ws + OFF_KP);
  u16*  Vt  = (u16*)(ws + OFF_VT);
  u16*  Qp  = (u16*)(ws + OFF_QP);

  // bf16 weights live in the head of AO: dead until attn writes AO (stream-ordered,
  // gemm_qkv completes before attn starts). 3 x 1M u16 = 6MB < 16MB.
  u16* wqb = AO;
  u16* wkb = AO + (size_t)CE*CE;
  u16* wvb = AO + (size_t)2*CE*CE;

  prep_kernel<<<3104,256,0,stream>>>(wq, wk, wv, wqb, wkb, wvb, kpm, maskf);

  gemm_qkv<<<dim3(256,3),512,0,stream>>>(query, key_, value, wqb, wkb, wvb,
                                         bq, bk, bv, Qp, Kp, Vt);

  attn_kernel<<<dim3(CB*CH, 8),256,0,stream>>>(Qp, Kp, Vt, maskf, AO);

  gemm_out<<<256,512,0,stream>>>(AO, wo, bo, (float*)d_out);
}

// Round 13
// 179.528 us; speedup vs baseline: 1.0753x; 1.0062x over previous
//
#include <hip/hip_runtime.h>

typedef unsigned short u16;
typedef unsigned int   u32;

using bf16x8 = __attribute__((ext_vector_type(8))) __bf16;
using f32x4  = __attribute__((ext_vector_type(4))) float;
using f32x16 = __attribute__((ext_vector_type(16))) float;
using u32x4  = __attribute__((ext_vector_type(4))) u32;

#define DEV static __device__ __forceinline__
#define GP(p) (const __attribute__((address_space(1))) void*)(p)
#define LP(p) (__attribute__((address_space(3))) void*)(p)
// fused counted-wait + barrier (T4)
#define WAITB(N) asm volatile("s_waitcnt vmcnt(" N ")\n\ts_barrier" ::: "memory")
// counted VMEM wait for reg-staged loads; sched_barrier pins register-only consumers (rule #18)
#define WAITVM(N) do{ asm volatile("s_waitcnt vmcnt(" N ")" ::: "memory"); \
                      __builtin_amdgcn_sched_barrier(0); }while(0)
// end-of-step: drain LDS ops then barrier
#define LGKMB asm volatile("s_waitcnt lgkmcnt(0)\n\ts_barrier" ::: "memory")

DEV u16 f2bf(float f){                      // RNE float->bf16
  u32 u = __builtin_bit_cast(u32, f);
  u32 r = u + 0x7fffu + ((u>>16)&1u);
  return (u16)(r>>16);
}
DEV float bcf(u32 x){ return __builtin_bit_cast(float, x); }
DEV bf16x8 as_bf(uint4 v){ return __builtin_bit_cast(bf16x8, v); }
DEV u32 cvt_pk(float lo, float hi){
  u32 r;
  asm("v_cvt_pk_bf16_f32 %0, %1, %2" : "=v"(r) : "v"(lo), "v"(hi));
  return r;
}
DEV void plswap(u32 &a, u32 &b){
  auto r = __builtin_amdgcn_permlane32_swap((int)a, (int)b, false, false);
  a = (u32)r[0]; b = (u32)r[1];
}
DEV float fexp2(float x){ float r; asm("v_exp_f32 %0, %1" : "=v"(r) : "v"(x)); return r; }
DEV float max3f(float a, float b, float c){
  float r; asm("v_max3_f32 %0, %1, %2, %3" : "=v"(r) : "v"(a), "v"(b), "v"(c)); return r;
}
DEV float fractf_(float x){ float r; asm("v_fract_f32 %0, %1" : "=v"(r) : "v"(x)); return r; }
DEV float sinrev(float f){ float r; asm("v_sin_f32 %0, %1" : "=v"(r) : "v"(f)); return r; }
DEV float cosrev(float f){ float r; asm("v_cos_f32 %0, %1" : "=v"(r) : "v"(f)); return r; }

// problem constants
constexpr int CB = 4, CL = 2048, CE = 1024, CH = 16, CD = 64;
constexpr int CM = CB*CL;           // 8192 rows
constexpr float LOG2E  = 1.44269504088896f;
constexpr float NEGBIG = -1.44269504e9f;    // -1e9 * log2e (exp2 domain)
constexpr float INV2PI = 0.15915494309189535f;

// ---------------- mask detect+convert AND weight cast, one launch ----------------
// blocks [0,3072): cast wq/wk/wv fp32->bf16 (3*2^18 float4 items)
// blocks [3072,3104): mask detect + convert (32 blocks x 256 = 8192 entries)
__global__ void prep_kernel(const float* __restrict__ wq, const float* __restrict__ wk,
                            const float* __restrict__ wv,
                            u16* __restrict__ oq, u16* __restrict__ ok, u16* __restrict__ ov,
                            const void* __restrict__ mask, float* __restrict__ maskf){
  if (blockIdx.x < 3072){
    int i = blockIdx.x*blockDim.x + threadIdx.x;
    int w = i >> 18, j = i & ((1<<18)-1);
    const float* in = (w==0)?wq:(w==1)?wk:wv;
    u16* out = (w==0)?oq:(w==1)?ok:ov;
    float4 a = ((const float4*)in)[j];
    ushort4 h;
    h.x = f2bf(a.x); h.y = f2bf(a.y); h.z = f2bf(a.z); h.w = f2bf(a.w);
    ((ushort4*)out)[j] = h;
    return;
  }
  __shared__ int a_gt1, a_badf, a_oddnz, a_evennz;
  if (threadIdx.x==0){ a_gt1=0; a_badf=0; a_oddnz=0; a_evennz=0; }
  __syncthreads();
  const u32* w = (const u32*)mask;
  int gt1=0, badf=0, oddnz=0, evennz=0;
  for (int i=threadIdx.x; i<2048; i+=256){
    u32 v = w[i];
    if (v > 1u) gt1 = 1;
    if (v != 0u && v != 0x3f800000u) badf = 1;
    if (v != 0u){ if (i & 1) oddnz = 1; else evennz = 1; }
  }
  if (gt1) atomicOr(&a_gt1,1);
  if (badf) atomicOr(&a_badf,1);
  if (oddnz) atomicOr(&a_oddnz,1);
  if (evennz) atomicOr(&a_evennz,1);
  __syncthreads();
  int mode;
  if (!a_gt1)           mode = (!a_oddnz && a_evennz) ? 3 : 0;
  else if (!a_badf)     mode = 1;
  else                  mode = 2;
  int i = (blockIdx.x-3072)*blockDim.x + threadIdx.x;   // B*L
  int v;
  if      (mode==0) v = ((const int*)mask)[i] != 0;
  else if (mode==1) v = ((const float*)mask)[i] != 0.f;
  else if (mode==3) v = ((const int*)mask)[2*i] != 0;
  else              v = ((const unsigned char*)mask)[i] != 0;
  maskf[i] = v ? NEGBIG : 0.f;
}

#define CVTW(dst, lo4, hi4) do{ \
  dst.x = cvt_pk(bcf(lo4.x), bcf(lo4.y)); \
  dst.y = cvt_pk(bcf(lo4.z), bcf(lo4.w)); \
  dst.z = cvt_pk(bcf(hi4.x), bcf(hi4.y)); \
  dst.w = cvt_pk(bcf(hi4.z), bcf(hi4.w)); \
}while(0)

// ---------------- QKV projection GEMM, hybrid staging + TRIPLE reg sets ----------------
// 256x128 tile, 8 waves, BK=64. Reused operand = bf16 via global_load_lds; streamed
// operand = fp32 reg-staged with cast-in-staging. 3 rotating reg sets so the
// fp32 stream's load is issued TWO steps before its confirming wait (2 steps ~
// 800-1000cyc >= HBM latency), with issues ordered (lds-op, reg-op) so the FIFO
// wait never force-confirms a young reg set. vmcnt ledgers hand-traced per step.
//  z<2 : A = activation fp32 reg-staged (8 ld/thr, sets S0/S1/S2),
//        B = weight bf16 gload_lds ring-4 (2 ld/thr).
//  z==2: A = wvb bf16 gload_lds ring-3 (4 ld/thr),
//        B = value fp32 reg-staged (4 ld/thr, sets R0/R1/R2).
// LDS 128KB carved per z. Banking: 128B rows, chunk ^= row&7 both sides (0 conflicts).
__global__ __launch_bounds__(512) void gemm_qkv(
    const float* __restrict__ query, const float* __restrict__ keyp,
    const float* __restrict__ value,
    const u16* __restrict__ wqb, const u16* __restrict__ wkb, const u16* __restrict__ wvb,
    const float* __restrict__ bq, const float* __restrict__ bk, const float* __restrict__ bv,
    u16* __restrict__ Qp, u16* __restrict__ Kp, u16* __restrict__ Vt)
{
  __shared__ u16 LDSU[65536];    // 128KB, carved per z
  const int z = blockIdx.y;
  const int tid=threadIdx.x, lane=tid&63, wid=tid>>6;
  const int llo=lane&15, lhi=lane>>4;
  int bid = blockIdx.x;                  // [0,256) per z
  int xcd = bid&7, j = bid>>3;           // j in [0,32)
  int mb, nb;
  if (z<2){ mb = xcd*4 + (j>>3); nb = j&7; }     // 32 x 8 tiles of 256x128
  else    { mb = j&3;  nb = xcd*8 + (j>>2); }    // 4 x 64 tiles (M=1024, N=8192)
  const int m0 = mb*256, n0 = nb*128;
  const int wr = wid>>1, wc = wid&1;     // 4M x 2N wave grid, 64x64 per wave
  const int rswA = llo&7;

  f32x4 acc[4][4] = {};

  auto COMP = [&](const u16* asrc, const u16* bsrc){
    const char* as = (const char*)asrc;
    const char* bs = (const char*)bsrc;
    #pragma unroll
    for (int ks=0; ks<2; ks++){
      bf16x8 af[4], bf_[4];
      #pragma unroll
      for (int mr=0;mr<4;mr++){
        int r = wr*64+mr*16+llo;
        af[mr] = as_bf(*(const uint4*)(as + r*128 + (((ks*4+lhi)^rswA)<<4)));
      }
      #pragma unroll
      for (int nr=0;nr<4;nr++){
        int r = wc*64+nr*16+llo;
        bf_[nr] = as_bf(*(const uint4*)(bs + r*128 + (((ks*4+lhi)^rswA)<<4)));
      }
      #pragma unroll
      for (int mr=0;mr<4;mr++)
        #pragma unroll
        for (int nr=0;nr<4;nr++)
          acc[mr][nr] = __builtin_amdgcn_mfma_f32_16x16x32_bf16(af[mr], bf_[nr], acc[mr][nr], 0,0,0);
    }
  };

  if (z < 2){
    const float* Af = z ? keyp : query;
    const u16*  Wb  = z ? wkb : wqb;
    u16* As0 = &LDSU[0];
    u16* As1 = &LDSU[16384];
    // B ring-4 slot s: &LDSU[32768 + s*8192]

    const float* aptr[4]; int aco[4];
    #pragma unroll
    for (int i=0;i<4;i++){
      int c = tid + i*512, row=c>>3, sc=(c&7)^(row&7);
      aptr[i] = Af + (size_t)(m0+row)*CE + sc*8;
      aco[i] = c*8;
    }
    u32x4 S0[8], S1[8], S2[8];           // TRIPLE reg sets: A(t) lives 3 steps

#define LOADA(T, RA) do{ \
  _Pragma("unroll") \
  for (int i=0;i<4;i++){ \
    asm volatile("global_load_dwordx4 %0, %2, off\n\tglobal_load_dwordx4 %1, %2, off offset:16" \
      : "=&v"((RA)[2*i]), "=&v"((RA)[2*i+1]) : "v"(aptr[i] + (size_t)(T)*64) : "memory"); \
  } \
}while(0)

#define STAGEB(T, SLOT) do{ \
  _Pragma("unroll") \
  for (int i=0;i<2;i++){ \
    int c = tid + i*512, row=c>>3, sc=(c&7)^(row&7); \
    __builtin_amdgcn_global_load_lds(GP(Wb + (size_t)(n0+row)*CE + (T)*64 + sc*8), \
                                     LP(&LDSU[32768 + (SLOT)*8192 + c*8]), 16, 0, 0); \
  } \
}while(0)

#define WRITEA(DST, RA) do{ \
  u16* _d = (DST); \
  _Pragma("unroll") \
  for (int i=0;i<4;i++){ \
    u32x4 w; CVTW(w, (RA)[2*i], (RA)[2*i+1]); \
    *(u32x4*)&_d[aco[i]] = w; \
  } \
}while(0)

// step T (0..12): stage B(T+2), issue A(T+3) into SL, wait WN (confirms through
// A(T+1), covering B(T)), flush A(T+1) from SW to LDS, compute tile T, barrier.
#define QSTEP(T, SL, SW, WN) do{ \
  STAGEB((T)+2, ((T)+2)&3); \
  LOADA((T)+3, SL); \
  WAITVM(WN); \
  WRITEA(((((T)+1)&1)?As1:As0), SW); \
  COMP((((T)&1)?As1:As0), &LDSU[32768 + ((T)&3)*8192]); \
  LGKMB; \
}while(0)

    // prologue: A0,B0,B1,A1,A2 in flight (28 loads); confirm A0 only (leave 20)
    LOADA(0, S0); STAGEB(0, 0); STAGEB(1, 1);
    LOADA(1, S1); LOADA(2, S2);
    WAITVM("20");
    WRITEA(As0, S0);
    LGKMB;

    QSTEP(0,  S0, S1, "18");   // A3->S0, flush A1
    QSTEP(1,  S1, S2, "20");   // A4->S1, flush A2
    QSTEP(2,  S2, S0, "20");
    QSTEP(3,  S0, S1, "20");
    QSTEP(4,  S1, S2, "20");
    QSTEP(5,  S2, S0, "20");
    QSTEP(6,  S0, S1, "20");
    QSTEP(7,  S1, S2, "20");
    QSTEP(8,  S2, S0, "20");
    QSTEP(9,  S0, S1, "20");
    QSTEP(10, S1, S2, "20");
    QSTEP(11, S2, S0, "20");
    QSTEP(12, S0, S1, "20");   // A15->S0, flush A13
    // t=13: stage B15 only; confirm through A14 (covers B13); flush A14
    STAGEB(15, 3);
    WAITVM("12");
    WRITEA(As0, S2);           // A14 -> As[14&1]=As0
    COMP(As1, &LDSU[32768 + 1*8192]);   // tile 13, slot 1
    LGKMB;
    // t=14: confirm through A15 (covers B14); flush A15
    WAITVM("2");
    WRITEA(As1, S0);           // A15 -> As[15&1]=As1
    COMP(As0, &LDSU[32768 + 2*8192]);   // tile 14, slot 2
    LGKMB;
    // t=15
    WAITVM("0");
    COMP(As1, &LDSU[32768 + 3*8192]);   // tile 15, slot 3

#undef LOADA
#undef STAGEB
#undef WRITEA
#undef QSTEP

    // ---- epilogue: bias + scale + RoPE + pack [B,H,L,D]
    const int colbase = n0 + wc*64;
    const float* bias = z ? bk : bq;
    u16* outp = z ? Kp : Qp;
    const float scale = z ? 1.f : 0.125f*LOG2E;
    const int h = colbase >> 6;           // wave covers exactly one head
    float b1[2], b2[2], invr[2];
    #pragma unroll
    for (int nr=0;nr<2;nr++){
      int j2 = nr*16 + llo;
      b1[nr] = bias[colbase + j2];
      b2[nr] = bias[colbase + j2 + 32];
      invr[nr] = exp2f(-(float)j2 * 0.41524101186092033f) * INV2PI;  // 10000^{-j2/32}/(2pi)
    }
    #pragma unroll
    for (int mr=0;mr<4;mr++)
      #pragma unroll
      for (int r=0;r<4;r++){
        int row = m0 + wr*64 + mr*16 + lhi*4 + r;
        int b = row >> 11, l = row & 2047;
        u16* dst = outp + (((size_t)(b*CH + h)*CL + l) << 6);
        #pragma unroll
        for (int nr=0;nr<2;nr++){
          int j2 = nr*16 + llo;
          float x1 = (acc[mr][nr][r]   + b1[nr]) * scale;
          float x2 = (acc[mr][nr+2][r] + b2[nr]) * scale;
          float fr = fractf_((float)l * invr[nr]);
          float sn = sinrev(fr), cs = cosrev(fr);
          dst[j2]      = f2bf(x1*cs - x2*sn);
          dst[j2 + 32] = f2bf(x2*cs + x1*sn);
        }
      }
  } else {
    // z==2: A = wvb bf16 gload_lds ring-3 (slots 0..2 at s*16384),
    //       B = value fp32 reg-staged, TRIPLE sets R0/R1/R2, dbuf Bs0/Bs1.
    u16* Bs0 = &LDSU[49152];
    u16* Bs1 = &LDSU[57344];

    const float* bptr[2]; int bco[2];
    #pragma unroll
    for (int i=0;i<2;i++){
      int c = tid + i*512, row=c>>3, sc=(c&7)^(row&7);
      bptr[i] = value + (size_t)(n0+row)*CE + sc*8;
      bco[i] = c*8;
    }
    u32x4 R0[4], R1[4], R2[4];

#define STAGEA(T, SLOT) do{ \
  _Pragma("unroll") \
  for (int i=0;i<4;i++){ \
    int c = tid + i*512, row=c>>3, sc=(c&7)^(row&7); \
    __builtin_amdgcn_global_load_lds(GP(wvb + (size_t)(m0+row)*CE + (T)*64 + sc*8), \
                                     LP(&LDSU[(SLOT)*16384 + c*8]), 16, 0, 0); \
  } \
}while(0)

#define LOADB(T, RB) do{ \
  _Pragma("unroll") \
  for (int i=0;i<2;i++){ \
    asm volatile("global_load_dwordx4 %0, %2, off\n\tglobal_load_dwordx4 %1, %2, off offset:16" \
      : "=&v"((RB)[2*i]), "=&v"((RB)[2*i+1]) : "v"(bptr[i] + (size_t)(T)*64) : "memory"); \
  } \
}while(0)

#define WRITEB(DST, RB) do{ \
  u16* _d = (DST); \
  _Pragma("unroll") \
  for (int i=0;i<2;i++){ \
    u32x4 w; CVTW(w, (RB)[2*i], (RB)[2*i+1]); \
    *(u32x4*)&_d[bco[i]] = w; \
  } \
}while(0)

// step T (0..12): stage A(T+2), issue B(T+3) into SL, wait WN (confirms through
// B(T+1), covering A(T)), flush B(T+1) from SW, compute tile T, barrier.
#define VSTEP(T, SL, SW, WN) do{ \
  STAGEA((T)+2, ((T)+2)%3); \
  LOADB((T)+3, SL); \
  WAITVM(WN); \
  WRITEB(((((T)+1)&1)?Bs1:Bs0), SW); \
  COMP(&LDSU[(((T))%3)*16384], (((T)&1)?Bs1:Bs0)); \
  LGKMB; \
}while(0)

    // prologue: A0,B0,A1,B1,B2 in flight (20 loads); confirm through B0 (leave 12)
    STAGEA(0,0); LOADB(0, R0);
    STAGEA(1,1); LOADB(1, R1);
    LOADB(2, R2);
    WAITVM("12");
    WRITEB(Bs0, R0);
    LGKMB;

    VSTEP(0,  R0, R1, "12");   // B3->R0, flush B1
    VSTEP(1,  R1, R2, "16");   // B4->R1, flush B2
    VSTEP(2,  R2, R0, "16");
    VSTEP(3,  R0, R1, "16");
    VSTEP(4,  R1, R2, "16");
    VSTEP(5,  R2, R0, "16");
    VSTEP(6,  R0, R1, "16");
    VSTEP(7,  R1, R2, "16");
    VSTEP(8,  R2, R0, "16");
    VSTEP(9,  R0, R1, "16");
    VSTEP(10, R1, R2, "16");
    VSTEP(11, R2, R0, "16");
    VSTEP(12, R0, R1, "16");   // B15->R0, flush B13
    // t=13: stage A15 only; confirm through B14 (covers A13); flush B14
    STAGEA(15, 0);
    WAITVM("12");
    WRITEB(Bs0, R2);           // B14 -> Bs[14&1]=Bs0
    COMP(&LDSU[1*16384], Bs1); // tile 13: A slot 13%3=1, Bs[13&1]=Bs1
    LGKMB;
    // t=14: confirm through B15 (covers A14); flush B15
    WAITVM("4");
    WRITEB(Bs1, R0);           // B15 -> Bs[15&1]=Bs1
    COMP(&LDSU[2*16384], Bs0); // tile 14: A slot 2, Bs0
    LGKMB;
    // t=15
    WAITVM("0");
    COMP(&LDSU[0*16384], Bs1); // tile 15: A slot 0, Bs1

#undef STAGEA
#undef LOADB
#undef WRITEB
#undef VSTEP

    // ---- epilogue: bias per row, write Vt [E][CM]
    const int colbase = n0 + wc*64;
    #pragma unroll
    for (int mr=0;mr<4;mr++)
      #pragma unroll
      for (int r=0;r<4;r++){
        int row = m0 + wr*64 + mr*16 + lhi*4 + r;
        float bvv = bv[row];
        #pragma unroll
        for (int nr=0;nr<4;nr++){
          int col = colbase + nr*16 + llo;
          Vt[(size_t)row*CM + col] = f2bf(acc[mr][nr][r] + bvv);
        }
      }
  }
}

// ---------------- output projection GEMM (fp32 out, bias per col) ----------------
// A = AO bf16 via global_load_lds ring-3; B = wo fp32 reg-staged (cast in staging).
__global__ __launch_bounds__(512) void gemm_out(
    const u16* __restrict__ A, const float* __restrict__ Btf,
    const float* __restrict__ bias, float* __restrict__ C)
{
  __shared__ u16 As[3][16384];   // 48KB
  __shared__ u16 Bs[2][8192];    // 32KB
  const int tid=threadIdx.x, lane=tid&63, wid=tid>>6;
  const int llo=lane&15, lhi=lane>>4;
  int bid = blockIdx.x;
  int xcd = bid&7, j = bid>>3;
  const int m0 = (xcd*4 + (j>>3))*256, n0 = (j&7)*128;   // 32 x 8 tiles of 256x128
  const int wr = wid>>1, wc = wid&1;
  const int rswA = llo&7;

  auto STAGEA = [&](int t, int buf){     // 4 gload_lds / thread
    #pragma unroll
    for (int i=0;i<4;i++){
      int c = tid + i*512, row=c>>3, sc=(c&7)^(row&7);
      __builtin_amdgcn_global_load_lds(GP(A + (size_t)(m0+row)*CE + t*64 + sc*8),
                                       LP(&As[buf][c*8]), 16, 0, 0);
    }
  };

  const float* bptr[2]; int bco[2];
  #pragma unroll
  for (int i=0;i<2;i++){
    int c = tid + i*512, row=c>>3, sc=(c&7)^(row&7);
    bptr[i] = Btf + (size_t)(n0+row)*CE + sc*8;
    bco[i] = c*8;
  }
  u32x4 B0[4], B1[4];

#define LOADB(T, RB) do{ \
  _Pragma("unroll") \
  for (int i=0;i<2;i++){ \
    asm volatile("global_load_dwordx4 %0, %2, off\n\tglobal_load_dwordx4 %1, %2, off offset:16" \
      : "=&v"((RB)[2*i]), "=&v"((RB)[2*i+1]) : "v"(bptr[i] + (size_t)(T)*64) : "memory"); \
  } \
}while(0)

#define WRITEB(BUF, RB) do{ \
  _Pragma("unroll") \
  for (int i=0;i<2;i++){ \
    u32x4 w; CVTW(w, (RB)[2*i], (RB)[2*i+1]); \
    *(u32x4*)&Bs[BUF][bco[i]] = w; \
  } \
}while(0)

  f32x4 acc[4][4] = {};

  auto COMP = [&](int abuf, int bbuf){
    const char* as = (const char*)As[abuf];
    const char* bs = (const char*)Bs[bbuf];
    #pragma unroll
    for (int ks=0; ks<2; ks++){
      bf16x8 af[4], bf_[4];
      #pragma unroll
      for (int mr=0;mr<4;mr++){
        int r = wr*64+mr*16+llo;
        af[mr] = as_bf(*(const uint4*)(as + r*128 + (((ks*4+lhi)^rswA)<<4)));
      }
      #pragma unroll
      for (int nr=0;nr<4;nr++){
        int r = wc*64+nr*16+llo;
        bf_[nr] = as_bf(*(const uint4*)(bs + r*128 + (((ks*4+lhi)^rswA)<<4)));
      }
      #pragma unroll
      for (int mr=0;mr<4;mr++)
        #pragma unroll
        for (int nr=0;nr<4;nr++)
          acc[mr][nr] = __builtin_amdgcn_mfma_f32_16x16x32_bf16(af[mr], bf_[nr], acc[mr][nr], 0,0,0);
    }
  };

  // prologue: A(0),B(0),A(1),B(1) in flight; confirm tile0 pair, write B0
  STAGEA(0,0); LOADB(0, B0);
  STAGEA(1,1); LOADB(1, B1);
  WAITVM("8");
  WRITEB(0, B0);
  LGKMB;

  #pragma unroll 1
  for (int jj=0; jj<7; jj++){
    const int t = 2*jj;
    STAGEA(t+2, (t+2)%3); LOADB(t+2, B0);
    WAITVM("8");
    WRITEB(1, B1);
    COMP(t%3, 0);
    LGKMB;
    STAGEA(t+3, (t+3)%3); LOADB(t+3, B1);
    WAITVM("8");
    WRITEB(0, B0);
    COMP((t+1)%3, 1);
    LGKMB;
  }
  WAITVM("0");
  WRITEB(1, B1);
  COMP(2, 0);          // t=14
  LGKMB;
  COMP(0, 1);          // t=15

#undef LOADB
#undef WRITEB

  #pragma unroll
  for (int mr=0;mr<4;mr++)
    #pragma unroll
    for (int nr=0;nr<4;nr++)
      #pragma unroll
      for (int r=0;r<4;r++){
        int row = m0 + wr*64 + mr*16 + lhi*4 + r;
        int col = n0 + wc*64 + nr*16 + llo;
        C[(size_t)row*CE + col] = acc[mr][nr][r] + bias[col];
      }
}

// ---------------- flash attention, T15 software pipeline ----------------
// Qp,Kp: [B*H, L, D] bf16 (Q pre-scaled by 0.125*log2e). Vt: [E, CM] bf16. Out AO [B,L,E] bf16.
__global__ __launch_bounds__(256,2) void attn_kernel(
    const u16* __restrict__ Qp, const u16* __restrict__ Kp, const u16* __restrict__ Vt,
    const float* __restrict__ maskf, u16* __restrict__ AO)
{
  __shared__ u16 K_lds[4][4096];   // ring of [kv64][d64] swizzled tiles
  __shared__ u16 V_lds[4][4096];   // ring of [d64][kv64] swizzled tiles
  __shared__ float M_lds[2048];    // padding mask row (exp2 domain) for this batch
  const int bh = blockIdx.x;
  const int slot = blockIdx.y;
  const int b = bh >> 4, h = bh & 15;
  const int tid=threadIdx.x, lane=tid&63, wid=tid>>6;
  const int l31 = lane&31, hi = lane>>5;
  const u16* Qh = Qp + (size_t)bh*CL*CD;
  const u16* Kh = Kp + (size_t)bh*CL*CD;
  const u16* Vhd = Vt + (size_t)(h*CD)*CM + b*CL;

  // stage padding-mask row once (8KB); confirmed by the first WAITB.
  #pragma unroll
  for (int i=0;i<2;i++)
    __builtin_amdgcn_global_load_lds(GP(maskf + b*CL + (i*256+tid)*4),
                                     LP(&M_lds[(i*256+tid)*4]), 16, 0, 0);

  auto STAGE = [&](int t, int buf){   // 4 gload_lds instructions per wave
    const u16* Ksrc = Kh + t*64*CD;
    const u16* Vsrc = Vhd + t*64;
    #pragma unroll
    for (int i=0;i<2;i++){
      int c = tid + i*256;
      int row = c>>3, sc = c&7;
      int c16 = sc ^ (row&7);
      __builtin_amdgcn_global_load_lds(GP(Ksrc + row*CD + c16*8),
                                       LP(&K_lds[buf][c*8]), 16, 0, 0);
      __builtin_amdgcn_global_load_lds(GP(Vsrc + (size_t)row*CM + c16*8),
                                       LP(&V_lds[buf][c*8]), 16, 0, 0);
    }
  };

  const int rowb = l31*128;            // LDS row byte base
  const int rsw  = (l31&7)<<4;
  const int qts2[2] = {15-slot, slot};

  for (int qi=0; qi<2; qi++){
    const int qt = qts2[qi];
    const int qw0 = qt*128 + wid*32;
    const int qlane = qw0 + l31;

    bf16x8 qf[4];
    #pragma unroll
    for (int c=0;c<4;c++)
      qf[c] = as_bf(*(const uint4*)(Qh + (size_t)qlane*CD + c*16 + hi*8));

    f32x16 o0 = {}, o1 = {};
    float m_r = -3e38f, l_r = 0.f;
    f32x16 sA0, sA1, sB0, sB1;         // double-banked S tiles

    const int nt = qt*2 + 2;
    STAGE(0,0); STAGE(1,1);

    // QK^T for tile t -> (d0,d1); Q carries 0.125*log2e
    auto QK = [&](int t, f32x16& d0, f32x16& d1){
      const char* kb = (const char*)K_lds[t&3];
      f32x16 z0 = {}, z1 = {};
      __builtin_amdgcn_s_setprio(1);
      #pragma unroll
      for (int c=0;c<4;c++){
        int cb = (c*32 + hi*16) ^ rsw;
        bf16x8 k0 = as_bf(*(const uint4*)(kb + rowb + cb));
        bf16x8 k1 = as_bf(*(const uint4*)(kb + 4096 + rowb + cb));
        z0 = __builtin_amdgcn_mfma_f32_32x32x16_bf16(k0, qf[c], z0, 0,0,0);
        z1 = __builtin_amdgcn_mfma_f32_32x32x16_bf16(k1, qf[c], z1, 0,0,0);
      }
      __builtin_amdgcn_s_setprio(0);
      d0 = z0; d1 = z1;
    };

    // softmax + PV for tile tp (S banks passed by ref; runs while QK(tp+1) drains)
    auto SMPV = [&](int tp, f32x16& s0, f32x16& s1){
      const int kv0 = tp*64;
      const char* vb = (const char*)V_lds[tp&3];

      // padding mask (broadcast LDS reads)
      f32x4 cm[8];
      #pragma unroll
      for (int s2=0;s2<2;s2++)
        #pragma unroll
        for (int g=0; g<4; g++)
          cm[s2*4+g] = *(const f32x4*)&M_lds[kv0 + s2*32 + g*8 + hi*4];

      // mask (+ causal on diagonal tiles), in place (exp2 domain)
      if (kv0 + 63 > qw0){
        #pragma unroll
        for (int s2=0;s2<2;s2++){
          f32x16& sv = s2 ? s1 : s0;
          #pragma unroll
          for (int reg=0; reg<16; reg++){
            int k = kv0 + s2*32 + (reg&3) + (reg>>2)*8 + hi*4;
            float v = sv[reg] + cm[s2*4+(reg>>2)][reg&3];
            sv[reg] = (k > qlane) ? v + NEGBIG : v;
          }
        }
      } else {
        #pragma unroll
        for (int s2=0;s2<2;s2++){
          f32x16& sv = s2 ? s1 : s0;
          #pragma unroll
          for (int reg=0; reg<16; reg++)
            sv[reg] = sv[reg] + cm[s2*4+(reg>>2)][reg&3];
        }
      }

      // row max
      f32x16 mx;
      #pragma unroll
      for (int r=0;r<16;r++) mx[r] = fmaxf(s0[r], s1[r]);
      float a0 = max3f(mx[0],mx[1],mx[2]);
      float a1 = max3f(mx[3],mx[4],mx[5]);
      float a2 = max3f(mx[6],mx[7],mx[8]);
      float a3 = max3f(mx[9],mx[10],mx[11]);
      float a4 = max3f(mx[12],mx[13],mx[14]);
      float vmax = fmaxf(max3f(a0,a1,a2), max3f(a3,a4,mx[15]));
      vmax = fmaxf(vmax, __shfl_xor(vmax, 32));

      // defer-max (T13)
      if (__any(vmax > m_r + 12.0f)){
        float mnew = fmaxf(m_r, vmax);
        float sc = fexp2(m_r - mnew);
        l_r *= sc;
        o0 *= sc; o1 *= sc;
        m_r = mnew;
      }

      // p = exp2(v - m)
      #pragma unroll
      for (int r=0;r<16;r++){
        s0[r] = fexp2(s0[r] - m_r);
        s1[r] = fexp2(s1[r] - m_r);
      }
      // row sum
      f32x16 sm = s0 + s1;
      #pragma unroll
      for (int w=8; w>=1; w>>=1)
        #pragma unroll
        for (int r=0;r<w;r++) sm[r] = sm[r] + sm[r+w];
      float rsum = sm[0];
      rsum += __shfl_xor(rsum, 32);
      l_r += rsum;

      // P -> bf16 B-fragments in-register
      u32 w_[16];
      #pragma unroll
      for (int s2=0;s2<2;s2++){
        f32x16& sv = s2 ? s1 : s0;
        #pragma unroll
        for (int c=0;c<2;c++){
          u32 a  = cvt_pk(sv[c*8+0], sv[c*8+1]);
          u32 bb = cvt_pk(sv[c*8+2], sv[c*8+3]);
          u32 cc = cvt_pk(sv[c*8+4], sv[c*8+5]);
          u32 dd = cvt_pk(sv[c*8+6], sv[c*8+7]);
          plswap(a, cc); plswap(bb, dd);
          int base = (s2*2+c)*4;
          w_[base+0]=a; w_[base+1]=bb; w_[base+2]=cc; w_[base+3]=dd;
        }
      }

      // O^T += V^T @ P^T
      __builtin_amdgcn_s_setprio(1);
      #pragma unroll
      for (int kc=0; kc<4; kc++){
        bf16x8 pf = as_bf(make_uint4(w_[kc*4], w_[kc*4+1], w_[kc*4+2], w_[kc*4+3]));
        int cb = (kc*32 + hi*16) ^ rsw;
        bf16x8 v0 = as_bf(*(const uint4*)(vb + rowb + cb));
        bf16x8 v1 = as_bf(*(const uint4*)(vb + 4096 + rowb + cb));
        o0 = __builtin_amdgcn_mfma_f32_32x32x16_bf16(v0, pf, o0, 0,0,0);
        o1 = __builtin_amdgcn_mfma_f32_32x32x16_bf16(v1, pf, o1, 0,0,0);
      }
      __builtin_amdgcn_s_setprio(0);
    };

    // t=0: QK only
    WAITB("4");                          // confirms S(0) (+mask, +qf)
    if (2 < nt) STAGE(2,2);
    QK(0, sA0, sA1);

    // pairs t=(2j+1, 2j+2), static S-bank parity
    #pragma unroll 1
    for (int jx=0; jx<qt; jx++){
      int t = 2*jx+1;                    // odd -> bank B
      WAITB("4");
      if (t+2 < nt) STAGE(t+2,(t+2)&3);
      QK(t, sB0, sB1);
      SMPV(t-1, sA0, sA1);
      t = 2*jx+2;                        // even -> bank A (never the last tile)
      WAITB("4");
      if (t+2 < nt) STAGE(t+2,(t+2)&3);
      QK(t, sA0, sA1);
      SMPV(t-1, sB0, sB1);
    }
    // t = nt-1 (odd)
    WAITB("0");
    QK(nt-1, sB0, sB1);
    SMPV(nt-2, sA0, sA1);
    // finish last tile
    SMPV(nt-1, sB0, sB1);

    // normalize + write O^T: lane has q=qlane, d = mt*32 + g*8 + hi*4 + {0..3}
    float inv = 1.f / l_r;
    u16* dst = AO + (size_t)(b*CL + qlane)*CE + h*CD;
    #pragma unroll
    for (int mt=0; mt<2; mt++){
      f32x16& ov = mt ? o1 : o0;
      #pragma unroll
      for (int g=0; g<4; g++){
        u32 lo  = cvt_pk(ov[g*4+0]*inv, ov[g*4+1]*inv);
        u32 hi2 = cvt_pk(ov[g*4+2]*inv, ov[g*4+3]*inv);
        *(uint2*)(dst + mt*32 + g*8 + hi*4) = make_uint2(lo, hi2);
      }
    }
    // protect ring reuse by qi=1 prologue (and reset vmcnt ledger)
    __syncthreads();
  }
}

// ---------------- launcher ----------------
extern "C" void kernel_launch(void* const* d_in, const int* in_sizes, int n_in,
                              void* d_out, int out_size, void* d_ws, size_t ws_size,
                              hipStream_t stream) {
  const float* query = (const float*)d_in[0];
  const float* key_  = (const float*)d_in[1];
  const float* value = (const float*)d_in[2];
  const float* wq = (const float*)d_in[3];
  const float* bq = (const float*)d_in[4];
  const float* wk = (const float*)d_in[5];
  const float* bk = (const float*)d_in[6];
  const float* wv = (const float*)d_in[7];
  const float* bv = (const float*)d_in[8];
  const float* wo = (const float*)d_in[9];
  const float* bo = (const float*)d_in[10];
  const void*  kpm = d_in[11];

  char* ws = (char*)d_ws;
  constexpr size_t SZ_ME_BF = (size_t)CM*CE*2;    // 16 MiB
  constexpr size_t OFF_MASKF= 256;
  constexpr size_t OFF_AO   = 65536;              // attn output, bf16 [B,L,E]
  constexpr size_t OFF_KP   = OFF_AO + SZ_ME_BF;
  constexpr size_t OFF_VT   = OFF_KP + SZ_ME_BF;  // Vt [1024][8192]
  constexpr size_t OFF_QP   = OFF_VT + SZ_ME_BF;

  float* maskf = (float*)(ws + OFF_MASKF);
  u16*  AO  = (u16*)(ws + OFF_AO);
  u16*  Kp  = (u16*)(ws + OFF_KP);
  u16*  Vt  = (u16*)(ws + OFF_VT);
  u16*  Qp  = (u16*)(ws + OFF_QP);

  // bf16 weights live in the head of AO: dead until attn writes AO (stream-ordered,
  // gemm_qkv completes before attn starts). 3 x 1M u16 = 6MB < 16MB.
  u16* wqb = AO;
  u16* wkb = AO + (size_t)CE*CE;
  u16* wvb = AO + (size_t)2*CE*CE;

  prep_kernel<<<3104,256,0,stream>>>(wq, wk, wv, wqb, wkb, wvb, kpm, maskf);

  gemm_qkv<<<dim3(256,3),512,0,stream>>>(query, key_, value, wqb, wkb, wvb,
                                         bq, bk, bv, Qp, Kp, Vt);

  attn_kernel<<<dim3(CB*CH, 8),256,0,stream>>>(Qp, Kp, Vt, maskf, AO);

  gemm_out<<<256,512,0,stream>>>(AO, wo, bo, (float*)d_out);
}